// Round 2
// baseline (2114.139 us; speedup 1.0000x reference)
//
#include <hip/hip_runtime.h>
#include <math.h>

#define D_DIM 1024
#define FF_DIM 4096
#define N_SEQ 257
#define B_SZ 40
#define H_CNT 16
#define HD_DIM 64
#define M_TOK (B_SZ * N_SEQ)   // 10280

typedef unsigned short u16;
typedef __bf16 bf16x8 __attribute__((ext_vector_type(8)));
typedef float f32x4 __attribute__((ext_vector_type(4)));

__device__ __forceinline__ float b2f(u16 u) {
    union { unsigned int i; float f; } x; x.i = ((unsigned int)u) << 16; return x.f;
}
__device__ __forceinline__ u16 f2b(float f) {
    union { float f; unsigned int i; } x; x.f = f;
    unsigned int r = x.i + 0x7FFFu + ((x.i >> 16) & 1u);  // round-to-nearest-even
    return (u16)(r >> 16);
}

// ---------------- fp32 -> bf16 weight conversion (n % 8 == 0) ----------------
__global__ __launch_bounds__(256)
void cvt_kernel(const float* __restrict__ in, u16* __restrict__ out, int n) {
    int i = (blockIdx.x * 256 + threadIdx.x) * 8;
    if (i >= n) return;
    float4 a = *(const float4*)(in + i);
    float4 b = *(const float4*)(in + i + 4);
    u16 o[8] = {f2b(a.x), f2b(a.y), f2b(a.z), f2b(a.w),
                f2b(b.x), f2b(b.y), f2b(b.z), f2b(b.w)};
    *(uint4*)(out + i) = *(const uint4*)o;
}

// ---------------- LayerNorm: one block (256 thr) per token row of 1024 ----------------
// in fp32, params fp32, out bf16
__global__ __launch_bounds__(256)
void ln_kernel(const float* __restrict__ in, const float* __restrict__ w,
               const float* __restrict__ b, u16* __restrict__ out) {
    const int row = blockIdx.x;
    const int t = threadIdx.x;
    const size_t base = (size_t)row * D_DIM;
    float x[4];
#pragma unroll
    for (int i = 0; i < 4; ++i) x[i] = in[base + t + i * 256];
    float s  = x[0] + x[1] + x[2] + x[3];
    float ss = x[0]*x[0] + x[1]*x[1] + x[2]*x[2] + x[3]*x[3];
#pragma unroll
    for (int o = 32; o > 0; o >>= 1) {
        s  += __shfl_xor(s, o, 64);
        ss += __shfl_xor(ss, o, 64);
    }
    __shared__ float sh_s[4], sh_ss[4];
    const int wave = t >> 6, lane = t & 63;
    if (lane == 0) { sh_s[wave] = s; sh_ss[wave] = ss; }
    __syncthreads();
    float S  = sh_s[0] + sh_s[1] + sh_s[2] + sh_s[3];
    float SS = sh_ss[0] + sh_ss[1] + sh_ss[2] + sh_ss[3];
    float mean = S * (1.0f / D_DIM);
    float var  = SS * (1.0f / D_DIM) - mean * mean;
    float rstd = rsqrtf(var + 1e-5f);
#pragma unroll
    for (int i = 0; i < 4; ++i) {
        int idx = t + i * 256;
        float y = (x[i] - mean) * rstd * w[idx] + b[idx];
        out[base + idx] = f2b(y);
    }
}

// ---------------- GEMM: C[m,n] = sum_k A[m,k]*Bt[n,k] (+ epilogue) ----------------
// A: [M,K] bf16 K-major. Bt: [N,K] bf16 K-major. K%32==0, N%64==0. M-edge guarded.
// 64x64 tile, BK=32, 4 waves; wave w owns rows [16w,16w+16), all 64 cols.
// MODE 0: out_bf16 = acc+bias            (k/v proj)
// MODE 1: out_bf16 = (acc+bias)*0.125    (q proj, pre-scaled)
// MODE 2: out_f32  = resid_f32 + acc + bias     (o proj + residual -> hid)
// MODE 3: out_bf16 = quickgelu(acc+bias)        (fc1)
// MODE 4: out_f32  = extra_f32 + acc + bias     (fc2 + residual -> d_out)
#define LDSS 40   // 80B row stride: 16B-aligned for b128, 2-way bank alias (free)
template <int MODE>
__global__ __launch_bounds__(256)
void gemm_kernel(const u16* __restrict__ A, const u16* __restrict__ Bt,
                 const float* __restrict__ bias, const float* __restrict__ extra,
                 void* __restrict__ out, int M, int N, int K) {
    __shared__ __align__(16) u16 sA[64 * LDSS];
    __shared__ __align__(16) u16 sB[64 * LDSS];
    const int t = threadIdx.x;
    const int m0 = blockIdx.x * 64;
    const int n0 = blockIdx.y * 64;
    const int wave = t >> 6, lane = t & 63;
    const int quad = lane >> 4, l16 = lane & 15;
    const int sr = t >> 2;            // staging row 0..63
    const int sk = (t & 3) << 3;      // staging k offset 0/8/16/24
    int gm = m0 + sr; if (gm > M - 1) gm = M - 1;   // clamp: no OOB / poison reads
    const size_t a_row = (size_t)gm * K + sk;
    const size_t b_row = (size_t)(n0 + sr) * K + sk;

    f32x4 acc[4] = {{0.f,0.f,0.f,0.f},{0.f,0.f,0.f,0.f},
                    {0.f,0.f,0.f,0.f},{0.f,0.f,0.f,0.f}};

    const int ar_off = (wave * 16 + l16) * LDSS + quad * 8;

    for (int k0 = 0; k0 < K; k0 += 32) {
        uint4 av = *(const uint4*)(A  + a_row + k0);
        uint4 bv = *(const uint4*)(Bt + b_row + k0);
        __syncthreads();
        *(uint4*)(sA + sr * LDSS + sk) = av;
        *(uint4*)(sB + sr * LDSS + sk) = bv;
        __syncthreads();
        bf16x8 a = *(const bf16x8*)(sA + ar_off);
#pragma unroll
        for (int nt = 0; nt < 4; ++nt) {
            bf16x8 bb = *(const bf16x8*)(sB + (nt * 16 + l16) * LDSS + quad * 8);
            acc[nt] = __builtin_amdgcn_mfma_f32_16x16x32_bf16(a, bb, acc[nt], 0, 0, 0);
        }
    }

    // C/D layout (m89-verified): col = lane&15, row = quad*4 + reg
#pragma unroll
    for (int nt = 0; nt < 4; ++nt) {
        const int n = n0 + nt * 16 + l16;
        const float bvf = bias[n];
#pragma unroll
        for (int i = 0; i < 4; ++i) {
            const int m = m0 + wave * 16 + quad * 4 + i;
            if (m >= M) continue;
            float v = acc[nt][i] + bvf;
            const size_t idx = (size_t)m * N + n;
            if (MODE == 0) {
                ((u16*)out)[idx] = f2b(v);
            } else if (MODE == 1) {
                ((u16*)out)[idx] = f2b(v * 0.125f);
            } else if (MODE == 2) {
                ((float*)out)[idx] = extra[idx] + v;
            } else if (MODE == 3) {
                float g = v / (1.0f + __expf(-1.702f * v));
                ((u16*)out)[idx] = f2b(g);
            } else {
                ((float*)out)[idx] = extra[idx] + v;
            }
        }
    }
}

// ---------------- Attention: one wave per (b,h,query-row) ----------------
// q/k/v layout: [b*N+t, D] bf16 with head slice at h*64. q pre-scaled by 0.125.
__global__ __launch_bounds__(64)
void attn_kernel(const u16* __restrict__ q, const u16* __restrict__ k,
                 const u16* __restrict__ v, u16* __restrict__ o) {
    const int lin = blockIdx.x;
    const int qi = lin % N_SEQ;
    const int bh = lin / N_SEQ;
    const int h = bh % H_CNT;
    const int b = bh / H_CNT;
    const int lane = threadIdx.x;
    __shared__ __align__(16) float qs[HD_DIM];
    __shared__ float pp[N_SEQ];
    const size_t head_off = (size_t)b * N_SEQ * D_DIM + (size_t)h * HD_DIM;
    const size_t qoff = head_off + (size_t)qi * D_DIM;
    qs[lane] = b2f(q[qoff + lane]);
    __syncthreads();
    float sc[5];
    float mx = -1e30f;
#pragma unroll
    for (int i = 0; i < 5; ++i) {
        int j = i * 64 + lane;
        float d = -1e30f;
        if (j < N_SEQ) {
            const u16* kr = k + head_off + (size_t)j * D_DIM;
            float acc = 0.f;
#pragma unroll
            for (int c = 0; c < 8; ++c) {
                uint4 kv4 = *(const uint4*)(kr + c * 8);
                const u16* kk = (const u16*)&kv4;
#pragma unroll
                for (int e = 0; e < 8; ++e) acc += b2f(kk[e]) * qs[c * 8 + e];
            }
            d = acc;
        }
        sc[i] = d;
        mx = fmaxf(mx, d);
    }
#pragma unroll
    for (int o2 = 32; o2 > 0; o2 >>= 1) mx = fmaxf(mx, __shfl_xor(mx, o2, 64));
    float sum = 0.f;
#pragma unroll
    for (int i = 0; i < 5; ++i) {
        int j = i * 64 + lane;
        float e = (j < N_SEQ) ? __expf(sc[i] - mx) : 0.f;
        sc[i] = e;
        sum += e;
    }
#pragma unroll
    for (int o2 = 32; o2 > 0; o2 >>= 1) sum += __shfl_xor(sum, o2, 64);
    const float inv = 1.0f / sum;
#pragma unroll
    for (int i = 0; i < 5; ++i) {
        int j = i * 64 + lane;
        if (j < N_SEQ) pp[j] = sc[i] * inv;
    }
    __syncthreads();
    float acc = 0.f;
    const u16* vbp = v + head_off + lane;
    for (int j = 0; j < N_SEQ; ++j) acc += pp[j] * b2f(vbp[(size_t)j * D_DIM]);
    o[qoff + lane] = f2b(acc);
}

extern "C" void kernel_launch(void* const* d_in, const int* in_sizes, int n_in,
                              void* d_out, int out_size, void* d_ws, size_t ws_size,
                              hipStream_t stream) {
    const float* hs   = (const float*)d_in[0];
    const float* ln1w = (const float*)d_in[1];
    const float* ln1b = (const float*)d_in[2];
    const float* wq   = (const float*)d_in[3];
    const float* bq   = (const float*)d_in[4];
    const float* wk   = (const float*)d_in[5];
    const float* bk   = (const float*)d_in[6];
    const float* wv   = (const float*)d_in[7];
    const float* bv   = (const float*)d_in[8];
    const float* wo   = (const float*)d_in[9];
    const float* bo   = (const float*)d_in[10];
    const float* ln2w = (const float*)d_in[11];
    const float* ln2b = (const float*)d_in[12];
    const float* w1   = (const float*)d_in[13];
    const float* b1   = (const float*)d_in[14];
    const float* w2   = (const float*)d_in[15];
    const float* b2   = (const float*)d_in[16];

    char* p = (char*)d_ws;
    size_t off = 0;
    auto alloc = [&](size_t bytes) {
        char* r = p + off;
        off += (bytes + 255) & ~(size_t)255;
        return (void*)r;
    };
    const int M = M_TOK;
    // bf16 weight copies (converted every call; ws is re-poisoned each launch)
    u16* wqb = (u16*)alloc((size_t)D_DIM * D_DIM * 2);
    u16* wkb = (u16*)alloc((size_t)D_DIM * D_DIM * 2);
    u16* wvb = (u16*)alloc((size_t)D_DIM * D_DIM * 2);
    u16* wob = (u16*)alloc((size_t)D_DIM * D_DIM * 2);
    u16* w1b = (u16*)alloc((size_t)FF_DIM * D_DIM * 2);
    u16* w2b = (u16*)alloc((size_t)D_DIM * FF_DIM * 2);
    // activations
    u16*  x_ln = (u16*) alloc((size_t)M * D_DIM * 2);   // reused as x_ln2
    u16*  qb   = (u16*) alloc((size_t)M * D_DIM * 2);
    u16*  kb   = (u16*) alloc((size_t)M * D_DIM * 2);
    u16*  vb2  = (u16*) alloc((size_t)M * D_DIM * 2);
    u16*  ab   = (u16*) alloc((size_t)M * D_DIM * 2);
    float* hid = (float*)alloc((size_t)M * D_DIM * 4);
    u16*  h1   = qb;  // aliases qb..ab (4*M*D*2 == M*FF*2); qkv/ab dead by then
    // total ws use ~165 MB

    const int nDD = D_DIM * D_DIM, nFD = FF_DIM * D_DIM;
    cvt_kernel<<<nDD / (256 * 8), 256, 0, stream>>>(wq, wqb, nDD);
    cvt_kernel<<<nDD / (256 * 8), 256, 0, stream>>>(wk, wkb, nDD);
    cvt_kernel<<<nDD / (256 * 8), 256, 0, stream>>>(wv, wvb, nDD);
    cvt_kernel<<<nDD / (256 * 8), 256, 0, stream>>>(wo, wob, nDD);
    cvt_kernel<<<nFD / (256 * 8), 256, 0, stream>>>(w1, w1b, nFD);
    cvt_kernel<<<nFD / (256 * 8), 256, 0, stream>>>(w2, w2b, nFD);

    ln_kernel<<<M, 256, 0, stream>>>(hs, ln1w, ln1b, x_ln);

    dim3 gD((M + 63) / 64, D_DIM / 64);
    gemm_kernel<1><<<gD, 256, 0, stream>>>(x_ln, wqb, bq, nullptr, qb,  M, D_DIM, D_DIM);
    gemm_kernel<0><<<gD, 256, 0, stream>>>(x_ln, wkb, bk, nullptr, kb,  M, D_DIM, D_DIM);
    gemm_kernel<0><<<gD, 256, 0, stream>>>(x_ln, wvb, bv, nullptr, vb2, M, D_DIM, D_DIM);

    attn_kernel<<<B_SZ * H_CNT * N_SEQ, 64, 0, stream>>>(qb, kb, vb2, ab);

    gemm_kernel<2><<<gD, 256, 0, stream>>>(ab, wob, bo, hs, hid, M, D_DIM, D_DIM);

    ln_kernel<<<M, 256, 0, stream>>>(hid, ln2w, ln2b, x_ln);

    dim3 gF((M + 63) / 64, FF_DIM / 64);
    gemm_kernel<3><<<gF, 256, 0, stream>>>(x_ln, w1b, b1, nullptr, h1, M, FF_DIM, D_DIM);
    gemm_kernel<4><<<gD, 256, 0, stream>>>(h1, w2b, b2, hid, (float*)d_out,
                                           M, D_DIM, FF_DIM);
}

// Round 3
// 1199.762 us; speedup vs baseline: 1.7621x; 1.7621x over previous
//
#include <hip/hip_runtime.h>
#include <math.h>

#define D_DIM 1024
#define FF_DIM 4096
#define N_SEQ 257
#define B_SZ 40
#define H_CNT 16
#define HD_DIM 64
#define M_TOK (B_SZ * N_SEQ)   // 10280

typedef unsigned short u16;
typedef __bf16 bf16x8 __attribute__((ext_vector_type(8)));
typedef float f32x4 __attribute__((ext_vector_type(4)));

__device__ __forceinline__ float b2f(u16 u) {
    union { unsigned int i; float f; } x; x.i = ((unsigned int)u) << 16; return x.f;
}
__device__ __forceinline__ u16 f2b(float f) {
    union { float f; unsigned int i; } x; x.f = f;
    unsigned int r = x.i + 0x7FFFu + ((x.i >> 16) & 1u);  // round-to-nearest-even
    return (u16)(r >> 16);
}

// ---------------- fp32 -> bf16 weight conversion (n % 8 == 0) ----------------
__global__ __launch_bounds__(256)
void cvt_kernel(const float* __restrict__ in, u16* __restrict__ out, int n) {
    int i = (blockIdx.x * 256 + threadIdx.x) * 8;
    if (i >= n) return;
    float4 a = *(const float4*)(in + i);
    float4 b = *(const float4*)(in + i + 4);
    u16 o[8] = {f2b(a.x), f2b(a.y), f2b(a.z), f2b(a.w),
                f2b(b.x), f2b(b.y), f2b(b.z), f2b(b.w)};
    *(uint4*)(out + i) = *(const uint4*)o;
}

// ---------------- LayerNorm: one block (256 thr) per token row of 1024 ----------------
__global__ __launch_bounds__(256)
void ln_kernel(const float* __restrict__ in, const float* __restrict__ w,
               const float* __restrict__ b, u16* __restrict__ out) {
    const int row = blockIdx.x;
    const int t = threadIdx.x;
    const size_t base = (size_t)row * D_DIM;
    float x[4];
#pragma unroll
    for (int i = 0; i < 4; ++i) x[i] = in[base + t + i * 256];
    float s  = x[0] + x[1] + x[2] + x[3];
    float ss = x[0]*x[0] + x[1]*x[1] + x[2]*x[2] + x[3]*x[3];
#pragma unroll
    for (int o = 32; o > 0; o >>= 1) {
        s  += __shfl_xor(s, o, 64);
        ss += __shfl_xor(ss, o, 64);
    }
    __shared__ float sh_s[4], sh_ss[4];
    const int wave = t >> 6, lane = t & 63;
    if (lane == 0) { sh_s[wave] = s; sh_ss[wave] = ss; }
    __syncthreads();
    float S  = sh_s[0] + sh_s[1] + sh_s[2] + sh_s[3];
    float SS = sh_ss[0] + sh_ss[1] + sh_ss[2] + sh_ss[3];
    float mean = S * (1.0f / D_DIM);
    float var  = SS * (1.0f / D_DIM) - mean * mean;
    float rstd = rsqrtf(var + 1e-5f);
#pragma unroll
    for (int i = 0; i < 4; ++i) {
        int idx = t + i * 256;
        float y = (x[i] - mean) * rstd * w[idx] + b[idx];
        out[base + idx] = f2b(y);
    }
}

// ---------------- GEMM: C[m,n] = sum_k A[m,k]*Bt[n,k] (+ epilogue) ----------------
#define LDSS 40
template <int MODE>
__global__ __launch_bounds__(256)
void gemm_kernel(const u16* __restrict__ A, const u16* __restrict__ Bt,
                 const float* __restrict__ bias, const float* __restrict__ extra,
                 void* __restrict__ out, int M, int N, int K) {
    __shared__ __align__(16) u16 sA[64 * LDSS];
    __shared__ __align__(16) u16 sB[64 * LDSS];
    const int t = threadIdx.x;
    const int m0 = blockIdx.x * 64;
    const int n0 = blockIdx.y * 64;
    const int wave = t >> 6, lane = t & 63;
    const int quad = lane >> 4, l16 = lane & 15;
    const int sr = t >> 2;
    const int sk = (t & 3) << 3;
    int gm = m0 + sr; if (gm > M - 1) gm = M - 1;
    const size_t a_row = (size_t)gm * K + sk;
    const size_t b_row = (size_t)(n0 + sr) * K + sk;

    f32x4 acc[4] = {{0.f,0.f,0.f,0.f},{0.f,0.f,0.f,0.f},
                    {0.f,0.f,0.f,0.f},{0.f,0.f,0.f,0.f}};

    const int ar_off = (wave * 16 + l16) * LDSS + quad * 8;

    for (int k0 = 0; k0 < K; k0 += 32) {
        uint4 av = *(const uint4*)(A  + a_row + k0);
        uint4 bv = *(const uint4*)(Bt + b_row + k0);
        __syncthreads();
        *(uint4*)(sA + sr * LDSS + sk) = av;
        *(uint4*)(sB + sr * LDSS + sk) = bv;
        __syncthreads();
        bf16x8 a = *(const bf16x8*)(sA + ar_off);
#pragma unroll
        for (int nt = 0; nt < 4; ++nt) {
            bf16x8 bb = *(const bf16x8*)(sB + (nt * 16 + l16) * LDSS + quad * 8);
            acc[nt] = __builtin_amdgcn_mfma_f32_16x16x32_bf16(a, bb, acc[nt], 0, 0, 0);
        }
    }

#pragma unroll
    for (int nt = 0; nt < 4; ++nt) {
        const int n = n0 + nt * 16 + l16;
        const float bvf = bias[n];
#pragma unroll
        for (int i = 0; i < 4; ++i) {
            const int m = m0 + wave * 16 + quad * 4 + i;
            if (m >= M) continue;
            float v = acc[nt][i] + bvf;
            const size_t idx = (size_t)m * N + n;
            if (MODE == 0) {
                ((u16*)out)[idx] = f2b(v);
            } else if (MODE == 1) {
                ((u16*)out)[idx] = f2b(v * 0.125f);
            } else if (MODE == 2) {
                ((float*)out)[idx] = extra[idx] + v;
            } else if (MODE == 3) {
                float g = v / (1.0f + __expf(-1.702f * v));
                ((u16*)out)[idx] = f2b(g);
            } else {
                ((float*)out)[idx] = extra[idx] + v;
            }
        }
    }
}

// ---------------- MFMA attention: one block per (q-tile 64, head, batch) ----------------
// q pre-scaled by 0.125. Layouts as in gemm: A-frag A[m=lane&15][k=quad*8+j],
// B-frag B[n=lane&15][k=quad*8+j], C/D col=lane&15 row=quad*4+reg.
#define ATT_SS 261   // scores stride (f32), odd -> spread banks
#define ATT_PS 328   // P stride (bf16), mult of 8 -> 16B-aligned b128 rows
#define ATT_KS 72    // K/Vt tile stride (bf16), mult of 8
__global__ __launch_bounds__(256)
void attn_mfma_kernel(const u16* __restrict__ q, const u16* __restrict__ k,
                      const u16* __restrict__ v, u16* __restrict__ o) {
    __shared__ __align__(16) u16 sKV[64 * ATT_KS];   // K-tile, then Vt-tile
    __shared__ float sS[64 * ATT_SS];                // raw scores (f32)
    __shared__ __align__(16) u16 sP[64 * ATT_PS];    // unnormalized P (bf16)
    __shared__ float sInv[64];                       // per-row 1/sum

    const int t = threadIdx.x;
    const int wave = t >> 6, lane = t & 63;
    const int quad = lane >> 4, l16 = lane & 15;
    const int qt = blockIdx.x;            // 0..4
    const int h  = blockIdx.y;
    const int b  = blockIdx.z;
    const int q0 = qt * 64;
    const size_t head = (size_t)b * N_SEQ * D_DIM + (size_t)h * HD_DIM;

    // Q fragments (held in regs for whole kernel)
    int qrow = q0 + wave * 16 + l16; if (qrow > N_SEQ - 1) qrow = N_SEQ - 1;
    const u16* qp = q + head + (size_t)qrow * D_DIM + quad * 8;
    bf16x8 qf0 = *(const bf16x8*)(qp);
    bf16x8 qf1 = *(const bf16x8*)(qp + 32);

    const int srow = t >> 2, seg = t & 3;   // staging: row 0..63, 2x 8-elem segs

    // ---- Phase 1: S = Q K^T over 5 key-tiles ----
    for (int kt = 0; kt < 5; ++kt) {
        const int j0 = kt * 64;
        int gj = j0 + srow; if (gj > N_SEQ - 1) gj = N_SEQ - 1;
        const u16* kr = k + head + (size_t)gj * D_DIM;
        uint4 k0v = *(const uint4*)(kr + seg * 8);
        uint4 k1v = *(const uint4*)(kr + seg * 8 + 32);
        __syncthreads();
        *(uint4*)(sKV + srow * ATT_KS + seg * 8)      = k0v;
        *(uint4*)(sKV + srow * ATT_KS + seg * 8 + 32) = k1v;
        __syncthreads();
        f32x4 acc[4] = {{0.f,0.f,0.f,0.f},{0.f,0.f,0.f,0.f},
                        {0.f,0.f,0.f,0.f},{0.f,0.f,0.f,0.f}};
#pragma unroll
        for (int nt = 0; nt < 4; ++nt) {
            bf16x8 b0 = *(const bf16x8*)(sKV + (nt * 16 + l16) * ATT_KS + quad * 8);
            bf16x8 b1 = *(const bf16x8*)(sKV + (nt * 16 + l16) * ATT_KS + quad * 8 + 32);
            acc[nt] = __builtin_amdgcn_mfma_f32_16x16x32_bf16(qf0, b0, acc[nt], 0, 0, 0);
            acc[nt] = __builtin_amdgcn_mfma_f32_16x16x32_bf16(qf1, b1, acc[nt], 0, 0, 0);
        }
#pragma unroll
        for (int nt = 0; nt < 4; ++nt) {
            const int col = j0 + nt * 16 + l16;
            if (col < N_SEQ) {
                const int row = wave * 16 + quad * 4;
#pragma unroll
                for (int i = 0; i < 4; ++i)
                    sS[(row + i) * ATT_SS + col] = acc[nt][i];
            }
        }
    }
    __syncthreads();

    // ---- Phase 2: softmax (4 lanes per row, chunks of 82 cover 0..328) ----
    {
        const int row = t >> 2, ck = t & 3;
        const int c0 = ck * 82;
        const int cs = (c0 + 82 < N_SEQ) ? c0 + 82 : N_SEQ;  // score scan end
        float mx = -1e30f;
        for (int j = c0; j < cs; ++j) mx = fmaxf(mx, sS[row * ATT_SS + j]);
        mx = fmaxf(mx, __shfl_xor(mx, 1, 64));
        mx = fmaxf(mx, __shfl_xor(mx, 2, 64));
        float sum = 0.f;
        for (int j = c0; j < c0 + 82; ++j) {
            float pj = 0.f;
            if (j < N_SEQ) { pj = __expf(sS[row * ATT_SS + j] - mx); sum += pj; }
            sP[row * ATT_PS + j] = f2b(pj);
        }
        sum += __shfl_xor(sum, 1, 64);
        sum += __shfl_xor(sum, 2, 64);
        if (ck == 0) sInv[row] = 1.0f / sum;
    }
    __syncthreads();

    // ---- Phase 3: O = P~ V, scaled by 1/sum in epilogue ----
    f32x4 oacc[4] = {{0.f,0.f,0.f,0.f},{0.f,0.f,0.f,0.f},
                     {0.f,0.f,0.f,0.f},{0.f,0.f,0.f,0.f}};
    for (int kt = 0; kt < 5; ++kt) {
        const int j0 = kt * 64;
        int gj = j0 + srow; if (gj > N_SEQ - 1) gj = N_SEQ - 1;
        const u16* vr = v + head + (size_t)gj * D_DIM;
        uint4 v0 = *(const uint4*)(vr + seg * 8);
        uint4 v1 = *(const uint4*)(vr + seg * 8 + 32);
        __syncthreads();
        const u16* ve0 = (const u16*)&v0;
        const u16* ve1 = (const u16*)&v1;
#pragma unroll
        for (int e = 0; e < 8; ++e) {
            sKV[(seg * 8 + e) * ATT_KS + srow]        = ve0[e];   // Vt[n][j]
            sKV[(seg * 8 + 32 + e) * ATT_KS + srow]   = ve1[e];
        }
        __syncthreads();
        bf16x8 p0 = *(const bf16x8*)(sP + (wave * 16 + l16) * ATT_PS + j0 + quad * 8);
        bf16x8 p1 = *(const bf16x8*)(sP + (wave * 16 + l16) * ATT_PS + j0 + quad * 8 + 32);
#pragma unroll
        for (int nt = 0; nt < 4; ++nt) {
            bf16x8 b0 = *(const bf16x8*)(sKV + (nt * 16 + l16) * ATT_KS + quad * 8);
            bf16x8 b1 = *(const bf16x8*)(sKV + (nt * 16 + l16) * ATT_KS + quad * 8 + 32);
            oacc[nt] = __builtin_amdgcn_mfma_f32_16x16x32_bf16(p0, b0, oacc[nt], 0, 0, 0);
            oacc[nt] = __builtin_amdgcn_mfma_f32_16x16x32_bf16(p1, b1, oacc[nt], 0, 0, 0);
        }
    }
#pragma unroll
    for (int nt = 0; nt < 4; ++nt) {
#pragma unroll
        for (int i = 0; i < 4; ++i) {
            const int mrow = wave * 16 + quad * 4 + i;
            const int m = q0 + mrow;
            if (m < N_SEQ) {
                o[head + (size_t)m * D_DIM + nt * 16 + l16] =
                    f2b(oacc[nt][i] * sInv[mrow]);
            }
        }
    }
}

extern "C" void kernel_launch(void* const* d_in, const int* in_sizes, int n_in,
                              void* d_out, int out_size, void* d_ws, size_t ws_size,
                              hipStream_t stream) {
    const float* hs   = (const float*)d_in[0];
    const float* ln1w = (const float*)d_in[1];
    const float* ln1b = (const float*)d_in[2];
    const float* wq   = (const float*)d_in[3];
    const float* bq   = (const float*)d_in[4];
    const float* wk   = (const float*)d_in[5];
    const float* bk   = (const float*)d_in[6];
    const float* wv   = (const float*)d_in[7];
    const float* bv   = (const float*)d_in[8];
    const float* wo   = (const float*)d_in[9];
    const float* bo   = (const float*)d_in[10];
    const float* ln2w = (const float*)d_in[11];
    const float* ln2b = (const float*)d_in[12];
    const float* w1   = (const float*)d_in[13];
    const float* b1   = (const float*)d_in[14];
    const float* w2   = (const float*)d_in[15];
    const float* b2   = (const float*)d_in[16];

    char* p = (char*)d_ws;
    size_t off = 0;
    auto alloc = [&](size_t bytes) {
        char* r = p + off;
        off += (bytes + 255) & ~(size_t)255;
        return (void*)r;
    };
    const int M = M_TOK;
    u16* wqb = (u16*)alloc((size_t)D_DIM * D_DIM * 2);
    u16* wkb = (u16*)alloc((size_t)D_DIM * D_DIM * 2);
    u16* wvb = (u16*)alloc((size_t)D_DIM * D_DIM * 2);
    u16* wob = (u16*)alloc((size_t)D_DIM * D_DIM * 2);
    u16* w1b = (u16*)alloc((size_t)FF_DIM * D_DIM * 2);
    u16* w2b = (u16*)alloc((size_t)D_DIM * FF_DIM * 2);
    u16*  x_ln = (u16*) alloc((size_t)M * D_DIM * 2);
    u16*  qb   = (u16*) alloc((size_t)M * D_DIM * 2);
    u16*  kb   = (u16*) alloc((size_t)M * D_DIM * 2);
    u16*  vb2  = (u16*) alloc((size_t)M * D_DIM * 2);
    u16*  ab   = (u16*) alloc((size_t)M * D_DIM * 2);
    float* hid = (float*)alloc((size_t)M * D_DIM * 4);
    u16*  h1   = qb;  // aliases qb..ab (4*M*D*2 == M*FF*2); qkv/ab dead by then

    const int nDD = D_DIM * D_DIM, nFD = FF_DIM * D_DIM;
    cvt_kernel<<<nDD / (256 * 8), 256, 0, stream>>>(wq, wqb, nDD);
    cvt_kernel<<<nDD / (256 * 8), 256, 0, stream>>>(wk, wkb, nDD);
    cvt_kernel<<<nDD / (256 * 8), 256, 0, stream>>>(wv, wvb, nDD);
    cvt_kernel<<<nDD / (256 * 8), 256, 0, stream>>>(wo, wob, nDD);
    cvt_kernel<<<nFD / (256 * 8), 256, 0, stream>>>(w1, w1b, nFD);
    cvt_kernel<<<nFD / (256 * 8), 256, 0, stream>>>(w2, w2b, nFD);

    ln_kernel<<<M, 256, 0, stream>>>(hs, ln1w, ln1b, x_ln);

    dim3 gD((M + 63) / 64, D_DIM / 64);
    gemm_kernel<1><<<gD, 256, 0, stream>>>(x_ln, wqb, bq, nullptr, qb,  M, D_DIM, D_DIM);
    gemm_kernel<0><<<gD, 256, 0, stream>>>(x_ln, wkb, bk, nullptr, kb,  M, D_DIM, D_DIM);
    gemm_kernel<0><<<gD, 256, 0, stream>>>(x_ln, wvb, bv, nullptr, vb2, M, D_DIM, D_DIM);

    dim3 gA(5, H_CNT, B_SZ);
    attn_mfma_kernel<<<gA, 256, 0, stream>>>(qb, kb, vb2, ab);

    gemm_kernel<2><<<gD, 256, 0, stream>>>(ab, wob, bo, hs, hid, M, D_DIM, D_DIM);

    ln_kernel<<<M, 256, 0, stream>>>(hid, ln2w, ln2b, x_ln);

    dim3 gF((M + 63) / 64, FF_DIM / 64);
    gemm_kernel<3><<<gF, 256, 0, stream>>>(x_ln, w1b, b1, nullptr, h1, M, FF_DIM, D_DIM);
    gemm_kernel<4><<<gD, 256, 0, stream>>>(h1, w2b, b2, hid, (float*)d_out,
                                           M, D_DIM, FF_DIM);
}

// Round 4
// 832.179 us; speedup vs baseline: 2.5405x; 1.4417x over previous
//
#include <hip/hip_runtime.h>
#include <math.h>

#define D_DIM 1024
#define FF_DIM 4096
#define N_SEQ 257
#define B_SZ 40
#define H_CNT 16
#define HD_DIM 64
#define M_TOK (B_SZ * N_SEQ)   // 10280

typedef unsigned short u16;
typedef __bf16 bf16x8 __attribute__((ext_vector_type(8)));
typedef float f32x4 __attribute__((ext_vector_type(4)));

__device__ __forceinline__ float b2f(u16 u) {
    union { unsigned int i; float f; } x; x.i = ((unsigned int)u) << 16; return x.f;
}
__device__ __forceinline__ u16 f2b(float f) {
    union { float f; unsigned int i; } x; x.f = f;
    unsigned int r = x.i + 0x7FFFu + ((x.i >> 16) & 1u);  // round-to-nearest-even
    return (u16)(r >> 16);
}

// async global->LDS 16B (dest = wave-uniform base + lane*16; contiguous layout)
__device__ __forceinline__ void g2lds16(const u16* g, u16* l) {
    __builtin_amdgcn_global_load_lds(
        (const __attribute__((address_space(1))) void*)g,
        (__attribute__((address_space(3))) void*)l,
        16, 0, 0);
}

// ---------------- fp32 -> bf16 weight conversion (n % 8 == 0) ----------------
__global__ __launch_bounds__(256)
void cvt_kernel(const float* __restrict__ in, u16* __restrict__ out, int n) {
    int i = (blockIdx.x * 256 + threadIdx.x) * 8;
    if (i >= n) return;
    float4 a = *(const float4*)(in + i);
    float4 b = *(const float4*)(in + i + 4);
    u16 o[8] = {f2b(a.x), f2b(a.y), f2b(a.z), f2b(a.w),
                f2b(b.x), f2b(b.y), f2b(b.z), f2b(b.w)};
    *(uint4*)(out + i) = *(const uint4*)o;
}

// ---------------- bias concat: [bq | bk | bv] -> f32[3072] ----------------
__global__ __launch_bounds__(256)
void bias_concat_kernel(const float* __restrict__ a, const float* __restrict__ b,
                        const float* __restrict__ c, float* __restrict__ out) {
    int i = blockIdx.x * 256 + threadIdx.x;
    if (i >= 3 * D_DIM) return;
    float v = (i < D_DIM) ? a[i] : (i < 2 * D_DIM ? b[i - D_DIM] : c[i - 2 * D_DIM]);
    out[i] = v;
}

// ---------------- LayerNorm: one block (256 thr) per token row of 1024 ----------------
__global__ __launch_bounds__(256)
void ln_kernel(const float* __restrict__ in, const float* __restrict__ w,
               const float* __restrict__ b, u16* __restrict__ out) {
    const int row = blockIdx.x;
    const int t = threadIdx.x;
    const size_t base = (size_t)row * D_DIM;
    float x[4];
#pragma unroll
    for (int i = 0; i < 4; ++i) x[i] = in[base + t + i * 256];
    float s  = x[0] + x[1] + x[2] + x[3];
    float ss = x[0]*x[0] + x[1]*x[1] + x[2]*x[2] + x[3]*x[3];
#pragma unroll
    for (int o = 32; o > 0; o >>= 1) {
        s  += __shfl_xor(s, o, 64);
        ss += __shfl_xor(ss, o, 64);
    }
    __shared__ float sh_s[4], sh_ss[4];
    const int wave = t >> 6, lane = t & 63;
    if (lane == 0) { sh_s[wave] = s; sh_ss[wave] = ss; }
    __syncthreads();
    float S  = sh_s[0] + sh_s[1] + sh_s[2] + sh_s[3];
    float SS = sh_ss[0] + sh_ss[1] + sh_ss[2] + sh_ss[3];
    float mean = S * (1.0f / D_DIM);
    float var  = SS * (1.0f / D_DIM) - mean * mean;
    float rstd = rsqrtf(var + 1e-5f);
#pragma unroll
    for (int i = 0; i < 4; ++i) {
        int idx = t + i * 256;
        float y = (x[i] - mean) * rstd * w[idx] + b[idx];
        out[base + idx] = f2b(y);
    }
}

// ---------------- GEMM 128x128: C[m,n] = sum_k A[m,k]*Bt[n,k] (+ epilogue) ----------------
// m97 structure: BK=64, global_load_lds width-16 staging, 4 waves x (4x4) 16x16x32 MFMA.
// LDS tiles [128][64] bf16, contiguous (stride 64 elems) as required by global_load_lds;
// bank spread via XOR of the 8-elem k-segment with (row&7) baked into the GLOBAL address.
// MODE 0: out_bf16 = acc+bias
// MODE 2: out_f32  = extra_f32 + acc + bias     (o proj / fc2 + residual)
// MODE 3: out_bf16 = quickgelu(acc+bias)        (fc1)
// MODE 5: QKV fused (N=3072): seg 0 -> out*0.125, seg 1 -> out2, seg 2 -> out3
template <int MODE>
__global__ __launch_bounds__(256)
void gemm_kernel(const u16* __restrict__ A, const u16* __restrict__ Bt,
                 const float* __restrict__ bias, const float* __restrict__ extra,
                 void* __restrict__ out, u16* __restrict__ out2, u16* __restrict__ out3,
                 int M, int N, int K) {
    __shared__ __align__(16) u16 sA[128 * 64];
    __shared__ __align__(16) u16 sB[128 * 64];
    const int t = threadIdx.x;
    const int m0 = blockIdx.x * 128;
    const int n0 = blockIdx.y * 128;
    const int wave = t >> 6, lane = t & 63;
    const int quad = lane >> 4, l16 = lane & 15;
    const int wm = (wave >> 1) * 64, wn = (wave & 1) * 64;

    // staging chunk descriptors: chunk c = i*256+t covers LDS bytes [c*16, +16)
    const u16* gA[4]; const u16* gB[4]; u16* lA[4]; u16* lB[4];
#pragma unroll
    for (int i = 0; i < 4; ++i) {
        const int c = i * 256 + t;
        const int row = c >> 3;
        const int sg = (c & 7) ^ (row & 7);   // XOR-swizzled global k-segment
        int gr = m0 + row; if (gr > M - 1) gr = M - 1;
        gA[i] = A  + (size_t)gr * K + sg * 8;
        gB[i] = Bt + (size_t)(n0 + row) * K + sg * 8;
        lA[i] = sA + c * 8;
        lB[i] = sB + c * 8;
    }

    f32x4 acc[4][4];
#pragma unroll
    for (int mt = 0; mt < 4; ++mt)
#pragma unroll
        for (int nt = 0; nt < 4; ++nt) acc[mt][nt] = {0.f, 0.f, 0.f, 0.f};

    for (int k0 = 0; k0 < K; k0 += 64) {
        __syncthreads();   // previous iter's ds_reads complete before overwrite
#pragma unroll
        for (int i = 0; i < 4; ++i) g2lds16(gA[i] + k0, lA[i]);
#pragma unroll
        for (int i = 0; i < 4; ++i) g2lds16(gB[i] + k0, lB[i]);
        __syncthreads();   // drains vmcnt -> staged data visible
#pragma unroll
        for (int j = 0; j < 2; ++j) {
            bf16x8 af[4], bfr[4];
#pragma unroll
            for (int mt = 0; mt < 4; ++mt) {
                const int r = wm + mt * 16 + l16;
                af[mt] = *(const bf16x8*)(sA + r * 64 + ((j * 4 + quad) ^ (r & 7)) * 8);
            }
#pragma unroll
            for (int nt = 0; nt < 4; ++nt) {
                const int n = wn + nt * 16 + l16;
                bfr[nt] = *(const bf16x8*)(sB + n * 64 + ((j * 4 + quad) ^ (n & 7)) * 8);
            }
#pragma unroll
            for (int mt = 0; mt < 4; ++mt)
#pragma unroll
                for (int nt = 0; nt < 4; ++nt)
                    acc[mt][nt] = __builtin_amdgcn_mfma_f32_16x16x32_bf16(
                        af[mt], bfr[nt], acc[mt][nt], 0, 0, 0);
        }
    }

    // C/D layout: col = lane&15, row = quad*4 + reg
#pragma unroll
    for (int mt = 0; mt < 4; ++mt) {
#pragma unroll
        for (int nt = 0; nt < 4; ++nt) {
            const int n = n0 + wn + nt * 16 + l16;
            const float bvf = bias[n];
#pragma unroll
            for (int i = 0; i < 4; ++i) {
                const int m = m0 + wm + mt * 16 + quad * 4 + i;
                if (m >= M) continue;
                float v = acc[mt][nt][i] + bvf;
                if (MODE == 0) {
                    ((u16*)out)[(size_t)m * N + n] = f2b(v);
                } else if (MODE == 2) {
                    const size_t idx = (size_t)m * N + n;
                    ((float*)out)[idx] = extra[idx] + v;
                } else if (MODE == 3) {
                    float g = v / (1.0f + __expf(-1.702f * v));
                    ((u16*)out)[(size_t)m * N + n] = f2b(g);
                } else {  // MODE 5: fused QKV split
                    const int seg = n >> 10, nl = n & 1023;
                    const size_t idx = (size_t)m * D_DIM + nl;
                    if (seg == 0)      ((u16*)out)[idx] = f2b(v * 0.125f);
                    else if (seg == 1) out2[idx] = f2b(v);
                    else               out3[idx] = f2b(v);
                }
            }
        }
    }
}

// ---------------- MFMA attention: one block per (q-tile 64, head, batch) ----------------
#define ATT_SS 261
#define ATT_PS 328
#define ATT_KS 72
__global__ __launch_bounds__(256)
void attn_mfma_kernel(const u16* __restrict__ q, const u16* __restrict__ k,
                      const u16* __restrict__ v, u16* __restrict__ o) {
    __shared__ __align__(16) u16 sKV[64 * ATT_KS];
    __shared__ float sS[64 * ATT_SS];
    __shared__ __align__(16) u16 sP[64 * ATT_PS];
    __shared__ float sInv[64];

    const int t = threadIdx.x;
    const int wave = t >> 6, lane = t & 63;
    const int quad = lane >> 4, l16 = lane & 15;
    const int qt = blockIdx.x;
    const int h  = blockIdx.y;
    const int b  = blockIdx.z;
    const int q0 = qt * 64;
    const size_t head = (size_t)b * N_SEQ * D_DIM + (size_t)h * HD_DIM;

    int qrow = q0 + wave * 16 + l16; if (qrow > N_SEQ - 1) qrow = N_SEQ - 1;
    const u16* qp = q + head + (size_t)qrow * D_DIM + quad * 8;
    bf16x8 qf0 = *(const bf16x8*)(qp);
    bf16x8 qf1 = *(const bf16x8*)(qp + 32);

    const int srow = t >> 2, seg = t & 3;

    for (int kt = 0; kt < 5; ++kt) {
        const int j0 = kt * 64;
        int gj = j0 + srow; if (gj > N_SEQ - 1) gj = N_SEQ - 1;
        const u16* kr = k + head + (size_t)gj * D_DIM;
        uint4 k0v = *(const uint4*)(kr + seg * 8);
        uint4 k1v = *(const uint4*)(kr + seg * 8 + 32);
        __syncthreads();
        *(uint4*)(sKV + srow * ATT_KS + seg * 8)      = k0v;
        *(uint4*)(sKV + srow * ATT_KS + seg * 8 + 32) = k1v;
        __syncthreads();
        f32x4 acc[4] = {{0.f,0.f,0.f,0.f},{0.f,0.f,0.f,0.f},
                        {0.f,0.f,0.f,0.f},{0.f,0.f,0.f,0.f}};
#pragma unroll
        for (int nt = 0; nt < 4; ++nt) {
            bf16x8 b0 = *(const bf16x8*)(sKV + (nt * 16 + l16) * ATT_KS + quad * 8);
            bf16x8 b1 = *(const bf16x8*)(sKV + (nt * 16 + l16) * ATT_KS + quad * 8 + 32);
            acc[nt] = __builtin_amdgcn_mfma_f32_16x16x32_bf16(qf0, b0, acc[nt], 0, 0, 0);
            acc[nt] = __builtin_amdgcn_mfma_f32_16x16x32_bf16(qf1, b1, acc[nt], 0, 0, 0);
        }
#pragma unroll
        for (int nt = 0; nt < 4; ++nt) {
            const int col = j0 + nt * 16 + l16;
            if (col < N_SEQ) {
                const int row = wave * 16 + quad * 4;
#pragma unroll
                for (int i = 0; i < 4; ++i)
                    sS[(row + i) * ATT_SS + col] = acc[nt][i];
            }
        }
    }
    __syncthreads();

    {
        const int row = t >> 2, ck = t & 3;
        const int c0 = ck * 82;
        const int cs = (c0 + 82 < N_SEQ) ? c0 + 82 : N_SEQ;
        float mx = -1e30f;
        for (int j = c0; j < cs; ++j) mx = fmaxf(mx, sS[row * ATT_SS + j]);
        mx = fmaxf(mx, __shfl_xor(mx, 1, 64));
        mx = fmaxf(mx, __shfl_xor(mx, 2, 64));
        float sum = 0.f;
        for (int j = c0; j < c0 + 82; ++j) {
            float pj = 0.f;
            if (j < N_SEQ) { pj = __expf(sS[row * ATT_SS + j] - mx); sum += pj; }
            sP[row * ATT_PS + j] = f2b(pj);
        }
        sum += __shfl_xor(sum, 1, 64);
        sum += __shfl_xor(sum, 2, 64);
        if (ck == 0) sInv[row] = 1.0f / sum;
    }
    __syncthreads();

    f32x4 oacc[4] = {{0.f,0.f,0.f,0.f},{0.f,0.f,0.f,0.f},
                     {0.f,0.f,0.f,0.f},{0.f,0.f,0.f,0.f}};
    for (int kt = 0; kt < 5; ++kt) {
        const int j0 = kt * 64;
        int gj = j0 + srow; if (gj > N_SEQ - 1) gj = N_SEQ - 1;
        const u16* vr = v + head + (size_t)gj * D_DIM;
        uint4 v0 = *(const uint4*)(vr + seg * 8);
        uint4 v1 = *(const uint4*)(vr + seg * 8 + 32);
        __syncthreads();
        const u16* ve0 = (const u16*)&v0;
        const u16* ve1 = (const u16*)&v1;
#pragma unroll
        for (int e = 0; e < 8; ++e) {
            sKV[(seg * 8 + e) * ATT_KS + srow]      = ve0[e];
            sKV[(seg * 8 + 32 + e) * ATT_KS + srow] = ve1[e];
        }
        __syncthreads();
        bf16x8 p0 = *(const bf16x8*)(sP + (wave * 16 + l16) * ATT_PS + j0 + quad * 8);
        bf16x8 p1 = *(const bf16x8*)(sP + (wave * 16 + l16) * ATT_PS + j0 + quad * 8 + 32);
#pragma unroll
        for (int nt = 0; nt < 4; ++nt) {
            bf16x8 b0 = *(const bf16x8*)(sKV + (nt * 16 + l16) * ATT_KS + quad * 8);
            bf16x8 b1 = *(const bf16x8*)(sKV + (nt * 16 + l16) * ATT_KS + quad * 8 + 32);
            oacc[nt] = __builtin_amdgcn_mfma_f32_16x16x32_bf16(p0, b0, oacc[nt], 0, 0, 0);
            oacc[nt] = __builtin_amdgcn_mfma_f32_16x16x32_bf16(p1, b1, oacc[nt], 0, 0, 0);
        }
    }
#pragma unroll
    for (int nt = 0; nt < 4; ++nt) {
#pragma unroll
        for (int i = 0; i < 4; ++i) {
            const int mrow = wave * 16 + quad * 4 + i;
            const int m = q0 + mrow;
            if (m < N_SEQ) {
                o[head + (size_t)m * D_DIM + nt * 16 + l16] =
                    f2b(oacc[nt][i] * sInv[mrow]);
            }
        }
    }
}

extern "C" void kernel_launch(void* const* d_in, const int* in_sizes, int n_in,
                              void* d_out, int out_size, void* d_ws, size_t ws_size,
                              hipStream_t stream) {
    const float* hs   = (const float*)d_in[0];
    const float* ln1w = (const float*)d_in[1];
    const float* ln1b = (const float*)d_in[2];
    const float* wq   = (const float*)d_in[3];
    const float* bq   = (const float*)d_in[4];
    const float* wk   = (const float*)d_in[5];
    const float* bk   = (const float*)d_in[6];
    const float* wv   = (const float*)d_in[7];
    const float* bv   = (const float*)d_in[8];
    const float* wo   = (const float*)d_in[9];
    const float* bo   = (const float*)d_in[10];
    const float* ln2w = (const float*)d_in[11];
    const float* ln2b = (const float*)d_in[12];
    const float* w1   = (const float*)d_in[13];
    const float* b1   = (const float*)d_in[14];
    const float* w2   = (const float*)d_in[15];
    const float* b2   = (const float*)d_in[16];

    char* p = (char*)d_ws;
    size_t off = 0;
    auto alloc = [&](size_t bytes) {
        char* r = p + off;
        off += (bytes + 255) & ~(size_t)255;
        return (void*)r;
    };
    const int M = M_TOK;
    u16* wqkvb = (u16*)alloc((size_t)3 * D_DIM * D_DIM * 2);  // [3072][1024]
    u16* wob   = (u16*)alloc((size_t)D_DIM * D_DIM * 2);
    u16* w1b   = (u16*)alloc((size_t)FF_DIM * D_DIM * 2);
    u16* w2b   = (u16*)alloc((size_t)D_DIM * FF_DIM * 2);
    float* bqkv = (float*)alloc((size_t)3 * D_DIM * 4);
    u16*  x_ln = (u16*) alloc((size_t)M * D_DIM * 2);
    u16*  qb   = (u16*) alloc((size_t)M * D_DIM * 2);
    u16*  kb   = (u16*) alloc((size_t)M * D_DIM * 2);
    u16*  vb2  = (u16*) alloc((size_t)M * D_DIM * 2);
    u16*  ab   = (u16*) alloc((size_t)M * D_DIM * 2);
    float* hid = (float*)alloc((size_t)M * D_DIM * 4);
    u16*  h1   = qb;  // aliases qb..ab (4*M*D*2 == M*FF*2); qkv/ab dead by then

    const int nDD = D_DIM * D_DIM, nFD = FF_DIM * D_DIM;
    cvt_kernel<<<nDD / (256 * 8), 256, 0, stream>>>(wq, wqkvb,            nDD);
    cvt_kernel<<<nDD / (256 * 8), 256, 0, stream>>>(wk, wqkvb + nDD,      nDD);
    cvt_kernel<<<nDD / (256 * 8), 256, 0, stream>>>(wv, wqkvb + 2 * nDD,  nDD);
    cvt_kernel<<<nDD / (256 * 8), 256, 0, stream>>>(wo, wob, nDD);
    cvt_kernel<<<nFD / (256 * 8), 256, 0, stream>>>(w1, w1b, nFD);
    cvt_kernel<<<nFD / (256 * 8), 256, 0, stream>>>(w2, w2b, nFD);
    bias_concat_kernel<<<12, 256, 0, stream>>>(bq, bk, bv, bqkv);

    ln_kernel<<<M, 256, 0, stream>>>(hs, ln1w, ln1b, x_ln);

    const int gM = (M + 127) / 128;  // 81
    dim3 gQKV(gM, 3 * D_DIM / 128);  // 81 x 24
    gemm_kernel<5><<<gQKV, 256, 0, stream>>>(x_ln, wqkvb, bqkv, nullptr,
                                             qb, kb, vb2, M, 3 * D_DIM, D_DIM);

    dim3 gA(5, H_CNT, B_SZ);
    attn_mfma_kernel<<<gA, 256, 0, stream>>>(qb, kb, vb2, ab);

    dim3 gD(gM, D_DIM / 128);        // 81 x 8
    gemm_kernel<2><<<gD, 256, 0, stream>>>(ab, wob, bo, hs, hid, nullptr, nullptr,
                                           M, D_DIM, D_DIM);

    ln_kernel<<<M, 256, 0, stream>>>(hid, ln2w, ln2b, x_ln);

    dim3 gF(gM, FF_DIM / 128);       // 81 x 32
    gemm_kernel<3><<<gF, 256, 0, stream>>>(x_ln, w1b, b1, nullptr, h1, nullptr, nullptr,
                                           M, FF_DIM, D_DIM);
    gemm_kernel<2><<<gD, 256, 0, stream>>>(h1, w2b, b2, hid, (float*)d_out,
                                           nullptr, nullptr, M, D_DIM, FF_DIM);
}

// Round 5
// 764.522 us; speedup vs baseline: 2.7653x; 1.0885x over previous
//
#include <hip/hip_runtime.h>
#include <math.h>

#define D_DIM 1024
#define FF_DIM 4096
#define N_SEQ 257
#define B_SZ 40
#define H_CNT 16
#define HD_DIM 64
#define M_TOK (B_SZ * N_SEQ)   // 10280
#define VT_NP 320               // padded key dim for vT (keys contiguous)

typedef unsigned short u16;
typedef __bf16 bf16x8 __attribute__((ext_vector_type(8)));
typedef float f32x4 __attribute__((ext_vector_type(4)));

__device__ __forceinline__ float b2f(u16 u) {
    union { unsigned int i; float f; } x; x.i = ((unsigned int)u) << 16; return x.f;
}
__device__ __forceinline__ u16 f2b(float f) {
    union { float f; unsigned int i; } x; x.f = f;
    unsigned int r = x.i + 0x7FFFu + ((x.i >> 16) & 1u);  // round-to-nearest-even
    return (u16)(r >> 16);
}

// async global->LDS 16B (dest = wave-uniform base + lane*16; contiguous layout)
__device__ __forceinline__ void g2lds16(const u16* g, u16* l) {
    __builtin_amdgcn_global_load_lds(
        (const __attribute__((address_space(1))) void*)g,
        (__attribute__((address_space(3))) void*)l,
        16, 0, 0);
}

// ---------------- fp32 -> bf16 weight conversion (n % 8 == 0) ----------------
__global__ __launch_bounds__(256)
void cvt_kernel(const float* __restrict__ in, u16* __restrict__ out, int n) {
    int i = (blockIdx.x * 256 + threadIdx.x) * 8;
    if (i >= n) return;
    float4 a = *(const float4*)(in + i);
    float4 b = *(const float4*)(in + i + 4);
    u16 o[8] = {f2b(a.x), f2b(a.y), f2b(a.z), f2b(a.w),
                f2b(b.x), f2b(b.y), f2b(b.z), f2b(b.w)};
    *(uint4*)(out + i) = *(const uint4*)o;
}

// ---------------- bias concat: [bq | bk | bv] -> f32[3072] ----------------
__global__ __launch_bounds__(256)
void bias_concat_kernel(const float* __restrict__ a, const float* __restrict__ b,
                        const float* __restrict__ c, float* __restrict__ out) {
    int i = blockIdx.x * 256 + threadIdx.x;
    if (i >= 3 * D_DIM) return;
    float v = (i < D_DIM) ? a[i] : (i < 2 * D_DIM ? b[i - D_DIM] : c[i - 2 * D_DIM]);
    out[i] = v;
}

// ---------------- LayerNorm: one block (256 thr) per token row of 1024 ----------------
__global__ __launch_bounds__(256)
void ln_kernel(const float* __restrict__ in, const float* __restrict__ w,
               const float* __restrict__ b, u16* __restrict__ out) {
    const int row = blockIdx.x;
    const int t = threadIdx.x;
    const size_t base = (size_t)row * D_DIM;
    float x[4];
#pragma unroll
    for (int i = 0; i < 4; ++i) x[i] = in[base + t + i * 256];
    float s  = x[0] + x[1] + x[2] + x[3];
    float ss = x[0]*x[0] + x[1]*x[1] + x[2]*x[2] + x[3]*x[3];
#pragma unroll
    for (int o = 32; o > 0; o >>= 1) {
        s  += __shfl_xor(s, o, 64);
        ss += __shfl_xor(ss, o, 64);
    }
    __shared__ float sh_s[4], sh_ss[4];
    const int wave = t >> 6, lane = t & 63;
    if (lane == 0) { sh_s[wave] = s; sh_ss[wave] = ss; }
    __syncthreads();
    float S  = sh_s[0] + sh_s[1] + sh_s[2] + sh_s[3];
    float SS = sh_ss[0] + sh_ss[1] + sh_ss[2] + sh_ss[3];
    float mean = S * (1.0f / D_DIM);
    float var  = SS * (1.0f / D_DIM) - mean * mean;
    float rstd = rsqrtf(var + 1e-5f);
#pragma unroll
    for (int i = 0; i < 4; ++i) {
        int idx = t + i * 256;
        float y = (x[i] - mean) * rstd * w[idx] + b[idx];
        out[base + idx] = f2b(y);
    }
}

// ---------------- GEMM 128x128 (m97 structure) ----------------
// MODE 0: out_bf16 = acc+bias
// MODE 2: out_f32  = extra_f32 + acc + bias     (o proj / fc2 + residual)
// MODE 3: out_bf16 = quickgelu(acc+bias)        (fc1)
// MODE 5: QKV fused (N=3072): seg0 -> q*0.125, seg1 -> k, seg2 -> vT scatter
template <int MODE>
__global__ __launch_bounds__(256)
void gemm_kernel(const u16* __restrict__ A, const u16* __restrict__ Bt,
                 const float* __restrict__ bias, const float* __restrict__ extra,
                 void* __restrict__ out, u16* __restrict__ out2, u16* __restrict__ out3,
                 int M, int N, int K) {
    __shared__ __align__(16) u16 sA[128 * 64];
    __shared__ __align__(16) u16 sB[128 * 64];
    const int t = threadIdx.x;
    const int m0 = blockIdx.x * 128;
    const int n0 = blockIdx.y * 128;
    const int wave = t >> 6, lane = t & 63;
    const int quad = lane >> 4, l16 = lane & 15;
    const int wm = (wave >> 1) * 64, wn = (wave & 1) * 64;

    const u16* gA[4]; const u16* gB[4]; u16* lA[4]; u16* lB[4];
#pragma unroll
    for (int i = 0; i < 4; ++i) {
        const int c = i * 256 + t;
        const int row = c >> 3;
        const int sg = (c & 7) ^ (row & 7);   // XOR-swizzled global k-segment
        int gr = m0 + row; if (gr > M - 1) gr = M - 1;
        gA[i] = A  + (size_t)gr * K + sg * 8;
        gB[i] = Bt + (size_t)(n0 + row) * K + sg * 8;
        lA[i] = sA + c * 8;
        lB[i] = sB + c * 8;
    }

    f32x4 acc[4][4];
#pragma unroll
    for (int mt = 0; mt < 4; ++mt)
#pragma unroll
        for (int nt = 0; nt < 4; ++nt) acc[mt][nt] = {0.f, 0.f, 0.f, 0.f};

    for (int k0 = 0; k0 < K; k0 += 64) {
        __syncthreads();
#pragma unroll
        for (int i = 0; i < 4; ++i) g2lds16(gA[i] + k0, lA[i]);
#pragma unroll
        for (int i = 0; i < 4; ++i) g2lds16(gB[i] + k0, lB[i]);
        __syncthreads();
#pragma unroll
        for (int j = 0; j < 2; ++j) {
            bf16x8 af[4], bfr[4];
#pragma unroll
            for (int mt = 0; mt < 4; ++mt) {
                const int r = wm + mt * 16 + l16;
                af[mt] = *(const bf16x8*)(sA + r * 64 + ((j * 4 + quad) ^ (r & 7)) * 8);
            }
#pragma unroll
            for (int nt = 0; nt < 4; ++nt) {
                const int n = wn + nt * 16 + l16;
                bfr[nt] = *(const bf16x8*)(sB + n * 64 + ((j * 4 + quad) ^ (n & 7)) * 8);
            }
#pragma unroll
            for (int mt = 0; mt < 4; ++mt)
#pragma unroll
                for (int nt = 0; nt < 4; ++nt)
                    acc[mt][nt] = __builtin_amdgcn_mfma_f32_16x16x32_bf16(
                        af[mt], bfr[nt], acc[mt][nt], 0, 0, 0);
        }
    }

    // C/D layout: col = lane&15, row = quad*4 + reg
#pragma unroll
    for (int mt = 0; mt < 4; ++mt) {
#pragma unroll
        for (int nt = 0; nt < 4; ++nt) {
            const int n = n0 + wn + nt * 16 + l16;
            const float bvf = bias[n];
#pragma unroll
            for (int i = 0; i < 4; ++i) {
                const int m = m0 + wm + mt * 16 + quad * 4 + i;
                if (m >= M) continue;
                float v = acc[mt][nt][i] + bvf;
                if (MODE == 0) {
                    ((u16*)out)[(size_t)m * N + n] = f2b(v);
                } else if (MODE == 2) {
                    const size_t idx = (size_t)m * N + n;
                    ((float*)out)[idx] = extra[idx] + v;
                } else if (MODE == 3) {
                    float g = v / (1.0f + __expf(-1.702f * v));
                    ((u16*)out)[(size_t)m * N + n] = f2b(g);
                } else {  // MODE 5: fused QKV split
                    const int seg = n >> 10, nl = n & 1023;
                    if (seg == 0) {
                        ((u16*)out)[(size_t)m * D_DIM + nl] = f2b(v * 0.125f);
                    } else if (seg == 1) {
                        out2[(size_t)m * D_DIM + nl] = f2b(v);
                    } else {
                        // vT[b*1024 + channel][tok_in_batch], keys contiguous
                        const int bb = m / N_SEQ;
                        const int tt = m - bb * N_SEQ;
                        out3[((size_t)bb * D_DIM + nl) * VT_NP + tt] = f2b(v);
                    }
                }
            }
        }
    }
}

// ---------------- MFMA attention v2: scores in registers, K/V from global ----------------
// One block per (q-tile 64, head, batch). q pre-scaled. LDS only for P round-trip.
// A-frag A[m=lane&15][k=quad*8+j]; B-frag B[n=lane&15][k=quad*8+j];
// C/D: col=lane&15, row=quad*4+reg.
#define ATT_PS 328   // P stride (bf16): mult of 8, 656B rows -> 2-way banks (free)
__global__ __launch_bounds__(256, 3)
void attn_mfma_kernel(const u16* __restrict__ q, const u16* __restrict__ k,
                      const u16* __restrict__ vT, u16* __restrict__ o) {
    __shared__ __align__(16) u16 sP[64 * ATT_PS];   // unnormalized P (bf16), 42 KB
    __shared__ float sInv[64];

    const int t = threadIdx.x;
    const int wave = t >> 6, lane = t & 63;
    const int quad = lane >> 4, l16 = lane & 15;
    const int q0 = blockIdx.x * 64;       // 0..4
    const int h  = blockIdx.y;
    const int b  = blockIdx.z;
    const size_t head = (size_t)b * N_SEQ * D_DIM + (size_t)h * HD_DIM;

    // Q fragments (A-operand, rows = wave's 16 q-rows)
    int qrow = q0 + wave * 16 + l16; if (qrow > N_SEQ - 1) qrow = N_SEQ - 1;
    const u16* qp = q + head + (size_t)qrow * D_DIM + quad * 8;
    bf16x8 qf0 = *(const bf16x8*)(qp);
    bf16x8 qf1 = *(const bf16x8*)(qp + 32);

    // ---- Phase 1: S = Q K^T, K fragments straight from global (natural layout) ----
    f32x4 s[5][4];
#pragma unroll
    for (int kt = 0; kt < 5; ++kt)
#pragma unroll
        for (int nt = 0; nt < 4; ++nt) s[kt][nt] = {0.f, 0.f, 0.f, 0.f};

#pragma unroll
    for (int kt = 0; kt < 5; ++kt) {
#pragma unroll
        for (int nt = 0; nt < 4; ++nt) {
            int key = kt * 64 + nt * 16 + l16;
            if (key > N_SEQ - 1) key = N_SEQ - 1;
            const u16* kr = k + head + (size_t)key * D_DIM + quad * 8;
            bf16x8 b0 = *(const bf16x8*)(kr);
            bf16x8 b1 = *(const bf16x8*)(kr + 32);
            s[kt][nt] = __builtin_amdgcn_mfma_f32_16x16x32_bf16(qf0, b0, s[kt][nt], 0, 0, 0);
            s[kt][nt] = __builtin_amdgcn_mfma_f32_16x16x32_bf16(qf1, b1, s[kt][nt], 0, 0, 0);
        }
    }

    // ---- Phase 2: softmax in registers (row r=quad*4+i lives in the 16 l16-lanes) ----
#pragma unroll
    for (int i = 0; i < 4; ++i) {
        float mx = -1e30f;
#pragma unroll
        for (int kt = 0; kt < 5; ++kt)
#pragma unroll
            for (int nt = 0; nt < 4; ++nt) {
                const bool valid = (kt < 4) || (nt == 0 && l16 == 0);  // col < 257
                if (valid) mx = fmaxf(mx, s[kt][nt][i]);
            }
        mx = fmaxf(mx, __shfl_xor(mx, 1, 64));
        mx = fmaxf(mx, __shfl_xor(mx, 2, 64));
        mx = fmaxf(mx, __shfl_xor(mx, 4, 64));
        mx = fmaxf(mx, __shfl_xor(mx, 8, 64));
        float sum = 0.f;
        const int prow = wave * 16 + quad * 4 + i;
#pragma unroll
        for (int kt = 0; kt < 5; ++kt)
#pragma unroll
            for (int nt = 0; nt < 4; ++nt) {
                const bool valid = (kt < 4) || (nt == 0 && l16 == 0);
                float pv = 0.f;
                if (valid) { pv = __expf(s[kt][nt][i] - mx); sum += pv; }
                sP[prow * ATT_PS + kt * 64 + nt * 16 + l16] = f2b(pv);
            }
        sum += __shfl_xor(sum, 1, 64);
        sum += __shfl_xor(sum, 2, 64);
        sum += __shfl_xor(sum, 4, 64);
        sum += __shfl_xor(sum, 8, 64);
        if (l16 == 0) sInv[prow] = 1.0f / sum;
    }
    __syncthreads();   // the only barrier: sP/sInv visible to all waves

    // ---- Phase 3: O = P~ V via vT (keys contiguous), scale by 1/sum in epilogue ----
    f32x4 oacc[4] = {{0.f,0.f,0.f,0.f},{0.f,0.f,0.f,0.f},
                     {0.f,0.f,0.f,0.f},{0.f,0.f,0.f,0.f}};
    const u16* vhead = vT + ((size_t)b * D_DIM + h * HD_DIM) * VT_NP;
#pragma unroll
    for (int kt = 0; kt < 5; ++kt) {
        const int j0 = kt * 64;
        bf16x8 p0 = *(const bf16x8*)(sP + (wave * 16 + l16) * ATT_PS + j0 + quad * 8);
        bf16x8 p1 = *(const bf16x8*)(sP + (wave * 16 + l16) * ATT_PS + j0 + quad * 8 + 32);
#pragma unroll
        for (int nt = 0; nt < 4; ++nt) {
            const u16* vr = vhead + (size_t)(nt * 16 + l16) * VT_NP + j0 + quad * 8;
            bf16x8 b0 = *(const bf16x8*)(vr);
            bf16x8 b1 = *(const bf16x8*)(vr + 32);
            oacc[nt] = __builtin_amdgcn_mfma_f32_16x16x32_bf16(p0, b0, oacc[nt], 0, 0, 0);
            oacc[nt] = __builtin_amdgcn_mfma_f32_16x16x32_bf16(p1, b1, oacc[nt], 0, 0, 0);
        }
    }
#pragma unroll
    for (int nt = 0; nt < 4; ++nt) {
#pragma unroll
        for (int i = 0; i < 4; ++i) {
            const int mrow = wave * 16 + quad * 4 + i;
            const int m = q0 + mrow;
            if (m < N_SEQ) {
                o[head + (size_t)m * D_DIM + nt * 16 + l16] =
                    f2b(oacc[nt][i] * sInv[mrow]);
            }
        }
    }
}

extern "C" void kernel_launch(void* const* d_in, const int* in_sizes, int n_in,
                              void* d_out, int out_size, void* d_ws, size_t ws_size,
                              hipStream_t stream) {
    const float* hs   = (const float*)d_in[0];
    const float* ln1w = (const float*)d_in[1];
    const float* ln1b = (const float*)d_in[2];
    const float* wq   = (const float*)d_in[3];
    const float* bq   = (const float*)d_in[4];
    const float* wk   = (const float*)d_in[5];
    const float* bk   = (const float*)d_in[6];
    const float* wv   = (const float*)d_in[7];
    const float* bv   = (const float*)d_in[8];
    const float* wo   = (const float*)d_in[9];
    const float* bo   = (const float*)d_in[10];
    const float* ln2w = (const float*)d_in[11];
    const float* ln2b = (const float*)d_in[12];
    const float* w1   = (const float*)d_in[13];
    const float* b1   = (const float*)d_in[14];
    const float* w2   = (const float*)d_in[15];
    const float* b2   = (const float*)d_in[16];

    char* p = (char*)d_ws;
    size_t off = 0;
    auto alloc = [&](size_t bytes) {
        char* r = p + off;
        off += (bytes + 255) & ~(size_t)255;
        return (void*)r;
    };
    const int M = M_TOK;
    u16* wqkvb = (u16*)alloc((size_t)3 * D_DIM * D_DIM * 2);  // [3072][1024]
    u16* wob   = (u16*)alloc((size_t)D_DIM * D_DIM * 2);
    u16* w1b   = (u16*)alloc((size_t)FF_DIM * D_DIM * 2);
    u16* w2b   = (u16*)alloc((size_t)D_DIM * FF_DIM * 2);
    float* bqkv = (float*)alloc((size_t)3 * D_DIM * 4);
    u16*  x_ln = (u16*) alloc((size_t)M * D_DIM * 2);
    u16*  qb   = (u16*) alloc((size_t)M * D_DIM * 2);
    u16*  kb   = (u16*) alloc((size_t)M * D_DIM * 2);
    u16*  vTb  = (u16*) alloc((size_t)B_SZ * D_DIM * VT_NP * 2);  // 26.2 MB
    u16*  ab   = (u16*) alloc((size_t)M * D_DIM * 2);
    float* hid = (float*)alloc((size_t)M * D_DIM * 4);
    u16*  h1   = qb;  // qb+kb+vT+ab span 89 MB >= M*FF*2 = 84 MB; all dead by FC1

    const int nDD = D_DIM * D_DIM, nFD = FF_DIM * D_DIM;
    cvt_kernel<<<nDD / (256 * 8), 256, 0, stream>>>(wq, wqkvb,            nDD);
    cvt_kernel<<<nDD / (256 * 8), 256, 0, stream>>>(wk, wqkvb + nDD,      nDD);
    cvt_kernel<<<nDD / (256 * 8), 256, 0, stream>>>(wv, wqkvb + 2 * nDD,  nDD);
    cvt_kernel<<<nDD / (256 * 8), 256, 0, stream>>>(wo, wob, nDD);
    cvt_kernel<<<nFD / (256 * 8), 256, 0, stream>>>(w1, w1b, nFD);
    cvt_kernel<<<nFD / (256 * 8), 256, 0, stream>>>(w2, w2b, nFD);
    bias_concat_kernel<<<12, 256, 0, stream>>>(bq, bk, bv, bqkv);

    ln_kernel<<<M, 256, 0, stream>>>(hs, ln1w, ln1b, x_ln);

    const int gM = (M + 127) / 128;  // 81
    dim3 gQKV(gM, 3 * D_DIM / 128);  // 81 x 24
    gemm_kernel<5><<<gQKV, 256, 0, stream>>>(x_ln, wqkvb, bqkv, nullptr,
                                             qb, kb, vTb, M, 3 * D_DIM, D_DIM);

    dim3 gA(5, H_CNT, B_SZ);
    attn_mfma_kernel<<<gA, 256, 0, stream>>>(qb, kb, vTb, ab);

    dim3 gD(gM, D_DIM / 128);        // 81 x 8
    gemm_kernel<2><<<gD, 256, 0, stream>>>(ab, wob, bo, hs, hid, nullptr, nullptr,
                                           M, D_DIM, D_DIM);

    ln_kernel<<<M, 256, 0, stream>>>(hid, ln2w, ln2b, x_ln);

    dim3 gF(gM, FF_DIM / 128);       // 81 x 32
    gemm_kernel<3><<<gF, 256, 0, stream>>>(x_ln, w1b, b1, nullptr, h1, nullptr, nullptr,
                                           M, FF_DIM, D_DIM);
    gemm_kernel<2><<<gD, 256, 0, stream>>>(h1, w2b, b2, hid, (float*)d_out,
                                           nullptr, nullptr, M, D_DIM, FF_DIM);
}

// Round 6
// 703.013 us; speedup vs baseline: 3.0073x; 1.0875x over previous
//
#include <hip/hip_runtime.h>
#include <math.h>

#define D_DIM 1024
#define FF_DIM 4096
#define N_SEQ 257
#define B_SZ 40
#define H_CNT 16
#define HD_DIM 64
#define M_TOK (B_SZ * N_SEQ)   // 10280
#define VT_NP 320               // padded key dim for vT (keys contiguous)

typedef unsigned short u16;
typedef __bf16 bf16x8 __attribute__((ext_vector_type(8)));
typedef float f32x4 __attribute__((ext_vector_type(4)));

__device__ __forceinline__ float b2f(u16 u) {
    union { unsigned int i; float f; } x; x.i = ((unsigned int)u) << 16; return x.f;
}
__device__ __forceinline__ u16 f2b(float f) {
    union { float f; unsigned int i; } x; x.f = f;
    unsigned int r = x.i + 0x7FFFu + ((x.i >> 16) & 1u);  // round-to-nearest-even
    return (u16)(r >> 16);
}

// async global->LDS 16B (dest = wave-uniform base + lane*16; contiguous layout)
__device__ __forceinline__ void g2lds16(const u16* g, u16* l) {
    __builtin_amdgcn_global_load_lds(
        (const __attribute__((address_space(1))) void*)g,
        (__attribute__((address_space(3))) void*)l,
        16, 0, 0);
}

// ---------------- fused fp32->bf16 weight conversion + bias concat ----------------
// wdst layout (contiguous): wqkv[3*nDD] | wo[nDD] | w1[nFD] | w2[nFD]
__global__ __launch_bounds__(256)
void cvt_all_kernel(const float* __restrict__ wq, const float* __restrict__ wk,
                    const float* __restrict__ wv, const float* __restrict__ wo,
                    const float* __restrict__ w1, const float* __restrict__ w2,
                    const float* __restrict__ bq, const float* __restrict__ bk,
                    const float* __restrict__ bv,
                    u16* __restrict__ wdst, float* __restrict__ bqkv) {
    const int nDD = D_DIM * D_DIM, nFD = FF_DIM * D_DIM;
    const int W8 = (4 * nDD + 2 * nFD) / 8;
    const int tid = blockIdx.x * 256 + threadIdx.x;
    if (tid < W8) {
        const int i = tid * 8;
        const float* src; int s;
        if (i < nDD)                { src = wq; s = i; }
        else if (i < 2 * nDD)       { src = wk; s = i - nDD; }
        else if (i < 3 * nDD)       { src = wv; s = i - 2 * nDD; }
        else if (i < 4 * nDD)       { src = wo; s = i - 3 * nDD; }
        else if (i < 4 * nDD + nFD) { src = w1; s = i - 4 * nDD; }
        else                        { src = w2; s = i - 4 * nDD - nFD; }
        float4 a = *(const float4*)(src + s);
        float4 b = *(const float4*)(src + s + 4);
        u16 o[8] = {f2b(a.x), f2b(a.y), f2b(a.z), f2b(a.w),
                    f2b(b.x), f2b(b.y), f2b(b.z), f2b(b.w)};
        *(uint4*)(wdst + i) = *(const uint4*)o;
    } else {
        const int j = tid - W8;
        if (j < 3 * D_DIM) {
            bqkv[j] = (j < D_DIM) ? bq[j]
                    : (j < 2 * D_DIM ? bk[j - D_DIM] : bv[j - 2 * D_DIM]);
        }
    }
}

// ---------------- LayerNorm: one block (256 thr) per token row of 1024 ----------------
__global__ __launch_bounds__(256)
void ln_kernel(const float* __restrict__ in, const float* __restrict__ w,
               const float* __restrict__ b, u16* __restrict__ out) {
    const int row = blockIdx.x;
    const int t = threadIdx.x;
    const size_t base = (size_t)row * D_DIM;
    float x[4];
#pragma unroll
    for (int i = 0; i < 4; ++i) x[i] = in[base + t + i * 256];
    float s  = x[0] + x[1] + x[2] + x[3];
    float ss = x[0]*x[0] + x[1]*x[1] + x[2]*x[2] + x[3]*x[3];
#pragma unroll
    for (int o = 32; o > 0; o >>= 1) {
        s  += __shfl_xor(s, o, 64);
        ss += __shfl_xor(ss, o, 64);
    }
    __shared__ float sh_s[4], sh_ss[4];
    const int wave = t >> 6, lane = t & 63;
    if (lane == 0) { sh_s[wave] = s; sh_ss[wave] = ss; }
    __syncthreads();
    float S  = sh_s[0] + sh_s[1] + sh_s[2] + sh_s[3];
    float SS = sh_ss[0] + sh_ss[1] + sh_ss[2] + sh_ss[3];
    float mean = S * (1.0f / D_DIM);
    float var  = SS * (1.0f / D_DIM) - mean * mean;
    float rstd = rsqrtf(var + 1e-5f);
#pragma unroll
    for (int i = 0; i < 4; ++i) {
        int idx = t + i * 256;
        float y = (x[i] - mean) * rstd * w[idx] + b[idx];
        out[base + idx] = f2b(y);
    }
}

// ---------------- GEMM 128x128 (m97 structure) + L2/XCD block swizzle ----------------
// Swizzle: sw m-blocks per chunk, n fastest within chunk -> per-chunk working set
// = sw A-tiles + all B-tiles (fits aggregate L2). Same-A blocks are span-strided in
// dispatch order -> land on the same XCD when span%8==0 (A-tile pinned in XCD L2).
// MODE 0: out_bf16 = acc+bias
// MODE 2: out_f32  = extra_f32 + acc + bias     (o proj / fc2 + residual)
// MODE 3: out_bf16 = quickgelu(acc+bias)        (fc1)
// MODE 5: QKV fused (N=3072): seg0 -> q*0.125, seg1 -> k, seg2 -> vT scatter
template <int MODE>
__global__ __launch_bounds__(256)
void gemm_kernel(const u16* __restrict__ A, const u16* __restrict__ Bt,
                 const float* __restrict__ bias, const float* __restrict__ extra,
                 void* __restrict__ out, u16* __restrict__ out2, u16* __restrict__ out3,
                 int M, int N, int K, int sw) {
    __shared__ __align__(16) u16 sA[128 * 64];
    __shared__ __align__(16) u16 sB[128 * 64];
    const int t = threadIdx.x;

    // block swizzle
    const int nM = gridDim.x, nN = gridDim.y;
    const int lid   = blockIdx.y * nM + blockIdx.x;   // dispatch order (x fastest)
    const int csz   = sw * nN;
    const int chunk = lid / csz;
    const int rem   = lid - chunk * csz;
    const int base  = chunk * sw;
    int span = nM - base; if (span > sw) span = sw;
    const int m0 = (base + rem % span) * 128;
    const int n0 = (rem / span) * 128;

    const int wave = t >> 6, lane = t & 63;
    const int quad = lane >> 4, l16 = lane & 15;
    const int wm = (wave >> 1) * 64, wn = (wave & 1) * 64;

    const u16* gA[4]; const u16* gB[4]; u16* lA[4]; u16* lB[4];
#pragma unroll
    for (int i = 0; i < 4; ++i) {
        const int c = i * 256 + t;
        const int row = c >> 3;
        const int sg = (c & 7) ^ (row & 7);   // XOR-swizzled global k-segment
        int gr = m0 + row; if (gr > M - 1) gr = M - 1;
        gA[i] = A  + (size_t)gr * K + sg * 8;
        gB[i] = Bt + (size_t)(n0 + row) * K + sg * 8;
        lA[i] = sA + c * 8;
        lB[i] = sB + c * 8;
    }

    f32x4 acc[4][4];
#pragma unroll
    for (int mt = 0; mt < 4; ++mt)
#pragma unroll
        for (int nt = 0; nt < 4; ++nt) acc[mt][nt] = {0.f, 0.f, 0.f, 0.f};

    for (int k0 = 0; k0 < K; k0 += 64) {
        __syncthreads();
#pragma unroll
        for (int i = 0; i < 4; ++i) g2lds16(gA[i] + k0, lA[i]);
#pragma unroll
        for (int i = 0; i < 4; ++i) g2lds16(gB[i] + k0, lB[i]);
        __syncthreads();
#pragma unroll
        for (int j = 0; j < 2; ++j) {
            bf16x8 af[4], bfr[4];
#pragma unroll
            for (int mt = 0; mt < 4; ++mt) {
                const int r = wm + mt * 16 + l16;
                af[mt] = *(const bf16x8*)(sA + r * 64 + ((j * 4 + quad) ^ (r & 7)) * 8);
            }
#pragma unroll
            for (int nt = 0; nt < 4; ++nt) {
                const int n = wn + nt * 16 + l16;
                bfr[nt] = *(const bf16x8*)(sB + n * 64 + ((j * 4 + quad) ^ (n & 7)) * 8);
            }
#pragma unroll
            for (int mt = 0; mt < 4; ++mt)
#pragma unroll
                for (int nt = 0; nt < 4; ++nt)
                    acc[mt][nt] = __builtin_amdgcn_mfma_f32_16x16x32_bf16(
                        af[mt], bfr[nt], acc[mt][nt], 0, 0, 0);
        }
    }

    // C/D layout: col = lane&15, row = quad*4 + reg
#pragma unroll
    for (int mt = 0; mt < 4; ++mt) {
#pragma unroll
        for (int nt = 0; nt < 4; ++nt) {
            const int n = n0 + wn + nt * 16 + l16;
            const float bvf = bias[n];
#pragma unroll
            for (int i = 0; i < 4; ++i) {
                const int m = m0 + wm + mt * 16 + quad * 4 + i;
                if (m >= M) continue;
                float v = acc[mt][nt][i] + bvf;
                if (MODE == 0) {
                    ((u16*)out)[(size_t)m * N + n] = f2b(v);
                } else if (MODE == 2) {
                    const size_t idx = (size_t)m * N + n;
                    ((float*)out)[idx] = extra[idx] + v;
                } else if (MODE == 3) {
                    float g = v / (1.0f + __expf(-1.702f * v));
                    ((u16*)out)[(size_t)m * N + n] = f2b(g);
                } else {  // MODE 5: fused QKV split
                    const int seg = n >> 10, nl = n & 1023;
                    if (seg == 0) {
                        ((u16*)out)[(size_t)m * D_DIM + nl] = f2b(v * 0.125f);
                    } else if (seg == 1) {
                        out2[(size_t)m * D_DIM + nl] = f2b(v);
                    } else {
                        // vT[b*1024 + channel][tok_in_batch], keys contiguous
                        const int bb = m / N_SEQ;
                        const int tt = m - bb * N_SEQ;
                        out3[((size_t)bb * D_DIM + nl) * VT_NP + tt] = f2b(v);
                    }
                }
            }
        }
    }
}

// ---------------- MFMA attention v2: scores in registers, K/V from global ----------------
#define ATT_PS 328   // P stride (bf16): mult of 8, 656B rows -> 2-way banks (free)
__global__ __launch_bounds__(256, 3)
void attn_mfma_kernel(const u16* __restrict__ q, const u16* __restrict__ k,
                      const u16* __restrict__ vT, u16* __restrict__ o) {
    __shared__ __align__(16) u16 sP[64 * ATT_PS];   // unnormalized P (bf16), 42 KB
    __shared__ float sInv[64];

    const int t = threadIdx.x;
    const int wave = t >> 6, lane = t & 63;
    const int quad = lane >> 4, l16 = lane & 15;
    const int q0 = blockIdx.x * 64;       // 0..4
    const int h  = blockIdx.y;
    const int b  = blockIdx.z;
    const size_t head = (size_t)b * N_SEQ * D_DIM + (size_t)h * HD_DIM;

    int qrow = q0 + wave * 16 + l16; if (qrow > N_SEQ - 1) qrow = N_SEQ - 1;
    const u16* qp = q + head + (size_t)qrow * D_DIM + quad * 8;
    bf16x8 qf0 = *(const bf16x8*)(qp);
    bf16x8 qf1 = *(const bf16x8*)(qp + 32);

    // ---- Phase 1: S = Q K^T, K fragments straight from global ----
    f32x4 s[5][4];
#pragma unroll
    for (int kt = 0; kt < 5; ++kt)
#pragma unroll
        for (int nt = 0; nt < 4; ++nt) s[kt][nt] = {0.f, 0.f, 0.f, 0.f};

#pragma unroll
    for (int kt = 0; kt < 5; ++kt) {
#pragma unroll
        for (int nt = 0; nt < 4; ++nt) {
            int key = kt * 64 + nt * 16 + l16;
            if (key > N_SEQ - 1) key = N_SEQ - 1;
            const u16* kr = k + head + (size_t)key * D_DIM + quad * 8;
            bf16x8 b0 = *(const bf16x8*)(kr);
            bf16x8 b1 = *(const bf16x8*)(kr + 32);
            s[kt][nt] = __builtin_amdgcn_mfma_f32_16x16x32_bf16(qf0, b0, s[kt][nt], 0, 0, 0);
            s[kt][nt] = __builtin_amdgcn_mfma_f32_16x16x32_bf16(qf1, b1, s[kt][nt], 0, 0, 0);
        }
    }

    // ---- Phase 2: softmax in registers ----
#pragma unroll
    for (int i = 0; i < 4; ++i) {
        float mx = -1e30f;
#pragma unroll
        for (int kt = 0; kt < 5; ++kt)
#pragma unroll
            for (int nt = 0; nt < 4; ++nt) {
                const bool valid = (kt < 4) || (nt == 0 && l16 == 0);  // col < 257
                if (valid) mx = fmaxf(mx, s[kt][nt][i]);
            }
        mx = fmaxf(mx, __shfl_xor(mx, 1, 64));
        mx = fmaxf(mx, __shfl_xor(mx, 2, 64));
        mx = fmaxf(mx, __shfl_xor(mx, 4, 64));
        mx = fmaxf(mx, __shfl_xor(mx, 8, 64));
        float sum = 0.f;
        const int prow = wave * 16 + quad * 4 + i;
#pragma unroll
        for (int kt = 0; kt < 5; ++kt)
#pragma unroll
            for (int nt = 0; nt < 4; ++nt) {
                const bool valid = (kt < 4) || (nt == 0 && l16 == 0);
                float pv = 0.f;
                if (valid) { pv = __expf(s[kt][nt][i] - mx); sum += pv; }
                sP[prow * ATT_PS + kt * 64 + nt * 16 + l16] = f2b(pv);
            }
        sum += __shfl_xor(sum, 1, 64);
        sum += __shfl_xor(sum, 2, 64);
        sum += __shfl_xor(sum, 4, 64);
        sum += __shfl_xor(sum, 8, 64);
        if (l16 == 0) sInv[prow] = 1.0f / sum;
    }
    __syncthreads();

    // ---- Phase 3: O = P~ V via vT, scale by 1/sum in epilogue ----
    f32x4 oacc[4] = {{0.f,0.f,0.f,0.f},{0.f,0.f,0.f,0.f},
                     {0.f,0.f,0.f,0.f},{0.f,0.f,0.f,0.f}};
    const u16* vhead = vT + ((size_t)b * D_DIM + h * HD_DIM) * VT_NP;
#pragma unroll
    for (int kt = 0; kt < 5; ++kt) {
        const int j0 = kt * 64;
        bf16x8 p0 = *(const bf16x8*)(sP + (wave * 16 + l16) * ATT_PS + j0 + quad * 8);
        bf16x8 p1 = *(const bf16x8*)(sP + (wave * 16 + l16) * ATT_PS + j0 + quad * 8 + 32);
#pragma unroll
        for (int nt = 0; nt < 4; ++nt) {
            const u16* vr = vhead + (size_t)(nt * 16 + l16) * VT_NP + j0 + quad * 8;
            bf16x8 b0 = *(const bf16x8*)(vr);
            bf16x8 b1 = *(const bf16x8*)(vr + 32);
            oacc[nt] = __builtin_amdgcn_mfma_f32_16x16x32_bf16(p0, b0, oacc[nt], 0, 0, 0);
            oacc[nt] = __builtin_amdgcn_mfma_f32_16x16x32_bf16(p1, b1, oacc[nt], 0, 0, 0);
        }
    }
#pragma unroll
    for (int nt = 0; nt < 4; ++nt) {
#pragma unroll
        for (int i = 0; i < 4; ++i) {
            const int mrow = wave * 16 + quad * 4 + i;
            const int m = q0 + mrow;
            if (m < N_SEQ) {
                o[head + (size_t)m * D_DIM + nt * 16 + l16] =
                    f2b(oacc[nt][i] * sInv[mrow]);
            }
        }
    }
}

extern "C" void kernel_launch(void* const* d_in, const int* in_sizes, int n_in,
                              void* d_out, int out_size, void* d_ws, size_t ws_size,
                              hipStream_t stream) {
    const float* hs   = (const float*)d_in[0];
    const float* ln1w = (const float*)d_in[1];
    const float* ln1b = (const float*)d_in[2];
    const float* wq   = (const float*)d_in[3];
    const float* bq   = (const float*)d_in[4];
    const float* wk   = (const float*)d_in[5];
    const float* bk   = (const float*)d_in[6];
    const float* wv   = (const float*)d_in[7];
    const float* bv   = (const float*)d_in[8];
    const float* wo   = (const float*)d_in[9];
    const float* bo   = (const float*)d_in[10];
    const float* ln2w = (const float*)d_in[11];
    const float* ln2b = (const float*)d_in[12];
    const float* w1   = (const float*)d_in[13];
    const float* b1   = (const float*)d_in[14];
    const float* w2   = (const float*)d_in[15];
    const float* b2   = (const float*)d_in[16];

    char* p = (char*)d_ws;
    size_t off = 0;
    auto alloc = [&](size_t bytes) {
        char* r = p + off;
        off += (bytes + 255) & ~(size_t)255;
        return (void*)r;
    };
    const int M = M_TOK;
    // weight block: MUST stay contiguous in this order (cvt_all writes linearly)
    u16* wqkvb = (u16*)alloc((size_t)3 * D_DIM * D_DIM * 2);  // [3072][1024]
    u16* wob   = (u16*)alloc((size_t)D_DIM * D_DIM * 2);
    u16* w1b   = (u16*)alloc((size_t)FF_DIM * D_DIM * 2);
    u16* w2b   = (u16*)alloc((size_t)D_DIM * FF_DIM * 2);
    float* bqkv = (float*)alloc((size_t)3 * D_DIM * 4);
    u16*  x_ln = (u16*) alloc((size_t)M * D_DIM * 2);
    u16*  qb   = (u16*) alloc((size_t)M * D_DIM * 2);
    u16*  kb   = (u16*) alloc((size_t)M * D_DIM * 2);
    u16*  vTb  = (u16*) alloc((size_t)B_SZ * D_DIM * VT_NP * 2);  // 26.2 MB
    u16*  ab   = (u16*) alloc((size_t)M * D_DIM * 2);
    float* hid = (float*)alloc((size_t)M * D_DIM * 4);
    u16*  h1   = qb;  // qb+kb+vT+ab span 89 MB >= M*FF*2 = 84 MB; all dead by FC1

    const int nDD = D_DIM * D_DIM, nFD = FF_DIM * D_DIM;
    const int W8 = (4 * nDD + 2 * nFD) / 8;
    cvt_all_kernel<<<(W8 + 3 * D_DIM + 255) / 256, 256, 0, stream>>>(
        wq, wk, wv, wo, w1, w2, bq, bk, bv, wqkvb, bqkv);

    ln_kernel<<<M, 256, 0, stream>>>(hs, ln1w, ln1b, x_ln);

    const int gM = (M + 127) / 128;  // 81
    dim3 gQKV(gM, 3 * D_DIM / 128);  // 81 x 24
    gemm_kernel<5><<<gQKV, 256, 0, stream>>>(x_ln, wqkvb, bqkv, nullptr,
                                             qb, kb, vTb, M, 3 * D_DIM, D_DIM, 16);

    dim3 gA(5, H_CNT, B_SZ);
    attn_mfma_kernel<<<gA, 256, 0, stream>>>(qb, kb, vTb, ab);

    dim3 gD(gM, D_DIM / 128);        // 81 x 8
    gemm_kernel<2><<<gD, 256, 0, stream>>>(ab, wob, bo, hs, hid, nullptr, nullptr,
                                           M, D_DIM, D_DIM, 16);

    ln_kernel<<<M, 256, 0, stream>>>(hid, ln2w, ln2b, x_ln);

    dim3 gF(gM, FF_DIM / 128);       // 81 x 32
    gemm_kernel<3><<<gF, 256, 0, stream>>>(x_ln, w1b, b1, nullptr, h1, nullptr, nullptr,
                                           M, FF_DIM, D_DIM, 16);
    gemm_kernel<2><<<gD, 256, 0, stream>>>(h1, w2b, b2, hid, (float*)d_out,
                                           nullptr, nullptr, M, D_DIM, FF_DIM, 4);
}

// Round 8
// 691.220 us; speedup vs baseline: 3.0586x; 1.0171x over previous
//
#include <hip/hip_runtime.h>
#include <math.h>

#define D_DIM 1024
#define FF_DIM 4096
#define N_SEQ 257
#define B_SZ 40
#define H_CNT 16
#define HD_DIM 64
#define M_TOK (B_SZ * N_SEQ)   // 10280
#define VT_NP 320               // padded key dim for vT (keys contiguous)

typedef unsigned short u16;
typedef __bf16 bf16x8 __attribute__((ext_vector_type(8)));
typedef float f32x4 __attribute__((ext_vector_type(4)));

__device__ __forceinline__ float b2f(u16 u) {
    union { unsigned int i; float f; } x; x.i = ((unsigned int)u) << 16; return x.f;
}
__device__ __forceinline__ u16 f2b(float f) {
    union { float f; unsigned int i; } x; x.f = f;
    unsigned int r = x.i + 0x7FFFu + ((x.i >> 16) & 1u);  // round-to-nearest-even
    return (u16)(r >> 16);
}

// async global->LDS 16B (dest = wave-uniform base + lane*16; contiguous layout)
__device__ __forceinline__ void g2lds16(const u16* g, u16* l) {
    __builtin_amdgcn_global_load_lds(
        (const __attribute__((address_space(1))) void*)g,
        (__attribute__((address_space(3))) void*)l,
        16, 0, 0);
}

// ---------------- fused fp32->bf16 weight conversion + bias concat ----------------
// wdst layout (contiguous): wqkv[3*nDD] | wo[nDD] | w1[nFD] | w2[nFD]
__global__ __launch_bounds__(256)
void cvt_all_kernel(const float* __restrict__ wq, const float* __restrict__ wk,
                    const float* __restrict__ wv, const float* __restrict__ wo,
                    const float* __restrict__ w1, const float* __restrict__ w2,
                    const float* __restrict__ bq, const float* __restrict__ bk,
                    const float* __restrict__ bv,
                    u16* __restrict__ wdst, float* __restrict__ bqkv) {
    const int nDD = D_DIM * D_DIM, nFD = FF_DIM * D_DIM;
    const int W8 = (4 * nDD + 2 * nFD) / 8;
    const int tid = blockIdx.x * 256 + threadIdx.x;
    if (tid < W8) {
        const int i = tid * 8;
        const float* src; int s;
        if (i < nDD)                { src = wq; s = i; }
        else if (i < 2 * nDD)       { src = wk; s = i - nDD; }
        else if (i < 3 * nDD)       { src = wv; s = i - 2 * nDD; }
        else if (i < 4 * nDD)       { src = wo; s = i - 3 * nDD; }
        else if (i < 4 * nDD + nFD) { src = w1; s = i - 4 * nDD; }
        else                        { src = w2; s = i - 4 * nDD - nFD; }
        float4 a = *(const float4*)(src + s);
        float4 b = *(const float4*)(src + s + 4);
        u16 o[8] = {f2b(a.x), f2b(a.y), f2b(a.z), f2b(a.w),
                    f2b(b.x), f2b(b.y), f2b(b.z), f2b(b.w)};
        *(uint4*)(wdst + i) = *(const uint4*)o;
    } else {
        const int j = tid - W8;
        if (j < 3 * D_DIM) {
            bqkv[j] = (j < D_DIM) ? bq[j]
                    : (j < 2 * D_DIM ? bk[j - D_DIM] : bv[j - 2 * D_DIM]);
        }
    }
}

// ---------------- LayerNorm: one block (256 thr) per token row of 1024 ----------------
__global__ __launch_bounds__(256)
void ln_kernel(const float* __restrict__ in, const float* __restrict__ w,
               const float* __restrict__ b, u16* __restrict__ out) {
    const int row = blockIdx.x;
    const int t = threadIdx.x;
    const size_t base = (size_t)row * D_DIM;
    float x[4];
#pragma unroll
    for (int i = 0; i < 4; ++i) x[i] = in[base + t + i * 256];
    float s  = x[0] + x[1] + x[2] + x[3];
    float ss = x[0]*x[0] + x[1]*x[1] + x[2]*x[2] + x[3]*x[3];
#pragma unroll
    for (int o = 32; o > 0; o >>= 1) {
        s  += __shfl_xor(s, o, 64);
        ss += __shfl_xor(ss, o, 64);
    }
    __shared__ float sh_s[4], sh_ss[4];
    const int wave = t >> 6, lane = t & 63;
    if (lane == 0) { sh_s[wave] = s; sh_ss[wave] = ss; }
    __syncthreads();
    float S  = sh_s[0] + sh_s[1] + sh_s[2] + sh_s[3];
    float SS = sh_ss[0] + sh_ss[1] + sh_ss[2] + sh_ss[3];
    float mean = S * (1.0f / D_DIM);
    float var  = SS * (1.0f / D_DIM) - mean * mean;
    float rstd = rsqrtf(var + 1e-5f);
#pragma unroll
    for (int i = 0; i < 4; ++i) {
        int idx = t + i * 256;
        float y = (x[i] - mean) * rstd * w[idx] + b[idx];
        out[base + idx] = f2b(y);
    }
}

// ---------------- GEMM 128x128 (m97 structure) + L2/XCD block swizzle ----------------
// MODE 0: out_bf16 = acc+bias
// MODE 2: out_f32  = extra_f32 + acc + bias     (o proj / fc2 + residual)
// MODE 3: out_bf16 = quickgelu(acc+bias)        (fc1)
// MODE 5: QKV fused (N=3072): seg0 -> q*0.125, seg1 -> k, seg2 -> vT scatter
template <int MODE>
__global__ __launch_bounds__(256)
void gemm_kernel(const u16* __restrict__ A, const u16* __restrict__ Bt,
                 const float* __restrict__ bias, const float* __restrict__ extra,
                 void* __restrict__ out, u16* __restrict__ out2, u16* __restrict__ out3,
                 int M, int N, int K, int sw) {
    __shared__ __align__(16) u16 sA[128 * 64];
    __shared__ __align__(16) u16 sB[128 * 64];
    const int t = threadIdx.x;

    // block swizzle
    const int nM = gridDim.x, nN = gridDim.y;
    const int lid   = blockIdx.y * nM + blockIdx.x;   // dispatch order (x fastest)
    const int csz   = sw * nN;
    const int chunk = lid / csz;
    const int rem   = lid - chunk * csz;
    const int base  = chunk * sw;
    int span = nM - base; if (span > sw) span = sw;
    const int m0 = (base + rem % span) * 128;
    const int n0 = (rem / span) * 128;

    const int wave = t >> 6, lane = t & 63;
    const int quad = lane >> 4, l16 = lane & 15;
    const int wm = (wave >> 1) * 64, wn = (wave & 1) * 64;

    const u16* gA[4]; const u16* gB[4]; u16* lA[4]; u16* lB[4];
#pragma unroll
    for (int i = 0; i < 4; ++i) {
        const int c = i * 256 + t;
        const int row = c >> 3;
        const int sg = (c & 7) ^ (row & 7);   // XOR-swizzled global k-segment
        int gr = m0 + row; if (gr > M - 1) gr = M - 1;
        gA[i] = A  + (size_t)gr * K + sg * 8;
        gB[i] = Bt + (size_t)(n0 + row) * K + sg * 8;
        lA[i] = sA + c * 8;
        lB[i] = sB + c * 8;
    }

    f32x4 acc[4][4];
#pragma unroll
    for (int mt = 0; mt < 4; ++mt)
#pragma unroll
        for (int nt = 0; nt < 4; ++nt) acc[mt][nt] = {0.f, 0.f, 0.f, 0.f};

    for (int k0 = 0; k0 < K; k0 += 64) {
        __syncthreads();
#pragma unroll
        for (int i = 0; i < 4; ++i) g2lds16(gA[i] + k0, lA[i]);
#pragma unroll
        for (int i = 0; i < 4; ++i) g2lds16(gB[i] + k0, lB[i]);
        __syncthreads();
#pragma unroll
        for (int j = 0; j < 2; ++j) {
            bf16x8 af[4], bfr[4];
#pragma unroll
            for (int mt = 0; mt < 4; ++mt) {
                const int r = wm + mt * 16 + l16;
                af[mt] = *(const bf16x8*)(sA + r * 64 + ((j * 4 + quad) ^ (r & 7)) * 8);
            }
#pragma unroll
            for (int nt = 0; nt < 4; ++nt) {
                const int n = wn + nt * 16 + l16;
                bfr[nt] = *(const bf16x8*)(sB + n * 64 + ((j * 4 + quad) ^ (n & 7)) * 8);
            }
#pragma unroll
            for (int mt = 0; mt < 4; ++mt)
#pragma unroll
                for (int nt = 0; nt < 4; ++nt)
                    acc[mt][nt] = __builtin_amdgcn_mfma_f32_16x16x32_bf16(
                        af[mt], bfr[nt], acc[mt][nt], 0, 0, 0);
        }
    }

    // C/D layout: col = lane&15, row = quad*4 + reg
#pragma unroll
    for (int mt = 0; mt < 4; ++mt) {
#pragma unroll
        for (int nt = 0; nt < 4; ++nt) {
            const int n = n0 + wn + nt * 16 + l16;
            const float bvf = bias[n];
#pragma unroll
            for (int i = 0; i < 4; ++i) {
                const int m = m0 + wm + mt * 16 + quad * 4 + i;
                if (m >= M) continue;
                float v = acc[mt][nt][i] + bvf;
                if (MODE == 0) {
                    ((u16*)out)[(size_t)m * N + n] = f2b(v);
                } else if (MODE == 2) {
                    const size_t idx = (size_t)m * N + n;
                    ((float*)out)[idx] = extra[idx] + v;
                } else if (MODE == 3) {
                    float g = v / (1.0f + __expf(-1.702f * v));
                    ((u16*)out)[(size_t)m * N + n] = f2b(g);
                } else {  // MODE 5: fused QKV split
                    const int seg = n >> 10, nl = n & 1023;
                    if (seg == 0) {
                        ((u16*)out)[(size_t)m * D_DIM + nl] = f2b(v * 0.125f);
                    } else if (seg == 1) {
                        out2[(size_t)m * D_DIM + nl] = f2b(v);
                    } else {
                        // vT[b*1024 + channel][tok_in_batch], keys contiguous
                        const int bb = m / N_SEQ;
                        const int tt = m - bb * N_SEQ;
                        out3[((size_t)bb * D_DIM + nl) * VT_NP + tt] = f2b(v);
                    }
                }
            }
        }
    }
}

// ---------------- MFMA attention v4: XCD-affine grid, 38KB LDS, one barrier ----------
// 1-D grid of 3200; decode puts the 5 q-tile blocks of one (b,h) on the SAME XCD
// (ids == same mod 8, 8 apart) so K/vT stay L2-resident.
// P stride 296 (=8*37): row stride 148 words, l16*20 mod 32 tiles all banks ->
// 2-way max on b128 reads (free). Max col 287 < 296, no swizzle needed.
// __syncthreads() after softmax is REQUIRED: sP is stored via u16* and read via
// __bf16-vector loads; without the barrier the compiler may reorder them (TBAA).
#define ATT_PS 296
__global__ __launch_bounds__(256, 4)
void attn_mfma_kernel(const u16* __restrict__ q, const u16* __restrict__ k,
                      const u16* __restrict__ vT, u16* __restrict__ o) {
    __shared__ __align__(16) u16 sP[64 * ATT_PS];   // 37 KB
    __shared__ float sInv[64];

    const int t = threadIdx.x;
    const int wave = t >> 6, lane = t & 63;
    const int quad = lane >> 4, l16 = lane & 15;

    // XCD-affine decode: lid = g*40 + qt*8 + x ; hb = g*8 + x
    const int lid = blockIdx.x;
    const int g = lid / 40, local = lid - g * 40;
    const int qt = local >> 3, x = local & 7;
    const int hb = g * 8 + x;
    const int h = hb & (H_CNT - 1), b = hb >> 4;
    const int q0 = qt * 64;
    const size_t head = (size_t)b * N_SEQ * D_DIM + (size_t)h * HD_DIM;

    int qrow = q0 + wave * 16 + l16; if (qrow > N_SEQ - 1) qrow = N_SEQ - 1;
    const u16* qp = q + head + (size_t)qrow * D_DIM + quad * 8;
    bf16x8 qf0 = *(const bf16x8*)(qp);
    bf16x8 qf1 = *(const bf16x8*)(qp + 32);

    // ---- Phase 1: S = Q K^T (keys 0..287; kt=4 only nt<2) ----
    f32x4 s[5][4];
#pragma unroll
    for (int kt = 0; kt < 5; ++kt) {
        const int ntMax = (kt == 4) ? 2 : 4;
#pragma unroll
        for (int nt = 0; nt < 4; ++nt) {
            if (nt >= ntMax) continue;
            s[kt][nt] = {0.f, 0.f, 0.f, 0.f};
            int key = kt * 64 + nt * 16 + l16;
            if (key > N_SEQ - 1) key = N_SEQ - 1;
            const u16* kr = k + head + (size_t)key * D_DIM + quad * 8;
            bf16x8 b0 = *(const bf16x8*)(kr);
            bf16x8 b1 = *(const bf16x8*)(kr + 32);
            s[kt][nt] = __builtin_amdgcn_mfma_f32_16x16x32_bf16(qf0, b0, s[kt][nt], 0, 0, 0);
            s[kt][nt] = __builtin_amdgcn_mfma_f32_16x16x32_bf16(qf1, b1, s[kt][nt], 0, 0, 0);
        }
    }

    // ---- Phase 2: softmax in registers; store unnormalized P (bf16) ----
#pragma unroll
    for (int i = 0; i < 4; ++i) {
        float mx = -1e30f;
#pragma unroll
        for (int kt = 0; kt < 5; ++kt) {
            const int ntMax = (kt == 4) ? 2 : 4;
#pragma unroll
            for (int nt = 0; nt < 4; ++nt) {
                if (nt >= ntMax) continue;
                const bool valid = (kt < 4) || (nt == 0 && l16 == 0);  // col < 257
                if (valid) mx = fmaxf(mx, s[kt][nt][i]);
            }
        }
        mx = fmaxf(mx, __shfl_xor(mx, 1, 64));
        mx = fmaxf(mx, __shfl_xor(mx, 2, 64));
        mx = fmaxf(mx, __shfl_xor(mx, 4, 64));
        mx = fmaxf(mx, __shfl_xor(mx, 8, 64));
        float sum = 0.f;
        const int prow = wave * 16 + quad * 4 + i;
#pragma unroll
        for (int kt = 0; kt < 5; ++kt) {
            const int ntMax = (kt == 4) ? 2 : 4;
#pragma unroll
            for (int nt = 0; nt < 4; ++nt) {
                if (nt >= ntMax) continue;
                const bool valid = (kt < 4) || (nt == 0 && l16 == 0);
                float pv = 0.f;
                if (valid) { pv = __expf(s[kt][nt][i] - mx); sum += pv; }
                sP[prow * ATT_PS + kt * 64 + nt * 16 + l16] = f2b(pv);
            }
        }
        sum += __shfl_xor(sum, 1, 64);
        sum += __shfl_xor(sum, 2, 64);
        sum += __shfl_xor(sum, 4, 64);
        sum += __shfl_xor(sum, 8, 64);
        if (l16 == 0) sInv[prow] = 1.0f / sum;
    }
    __syncthreads();   // required: orders u16 stores vs bf16-vector loads of sP

    // ---- Phase 3: O = P~ V via vT, scale by 1/sum in epilogue ----
    f32x4 oacc[4] = {{0.f,0.f,0.f,0.f},{0.f,0.f,0.f,0.f},
                     {0.f,0.f,0.f,0.f},{0.f,0.f,0.f,0.f}};
    const u16* vhead = vT + ((size_t)b * D_DIM + h * HD_DIM) * VT_NP;
    const int prr = wave * 16 + l16;     // P row this lane reads (A-operand m)
#pragma unroll
    for (int kt = 0; kt < 5; ++kt) {
        const int j0 = kt * 64;
        bf16x8 p0 = *(const bf16x8*)(sP + prr * ATT_PS + j0 + quad * 8);
        bf16x8 p1;
        if (kt < 4) p1 = *(const bf16x8*)(sP + prr * ATT_PS + j0 + quad * 8 + 32);
#pragma unroll
        for (int nt = 0; nt < 4; ++nt) {
            const u16* vr = vhead + (size_t)(nt * 16 + l16) * VT_NP + j0 + quad * 8;
            bf16x8 b0 = *(const bf16x8*)(vr);
            oacc[nt] = __builtin_amdgcn_mfma_f32_16x16x32_bf16(p0, b0, oacc[nt], 0, 0, 0);
            if (kt < 4) {
                bf16x8 b1 = *(const bf16x8*)(vr + 32);
                oacc[nt] = __builtin_amdgcn_mfma_f32_16x16x32_bf16(p1, b1, oacc[nt], 0, 0, 0);
            }
        }
    }
#pragma unroll
    for (int nt = 0; nt < 4; ++nt) {
#pragma unroll
        for (int i = 0; i < 4; ++i) {
            const int mrow = wave * 16 + quad * 4 + i;
            const int m = q0 + mrow;
            if (m < N_SEQ) {
                o[head + (size_t)m * D_DIM + nt * 16 + l16] =
                    f2b(oacc[nt][i] * sInv[mrow]);
            }
        }
    }
}

extern "C" void kernel_launch(void* const* d_in, const int* in_sizes, int n_in,
                              void* d_out, int out_size, void* d_ws, size_t ws_size,
                              hipStream_t stream) {
    const float* hs   = (const float*)d_in[0];
    const float* ln1w = (const float*)d_in[1];
    const float* ln1b = (const float*)d_in[2];
    const float* wq   = (const float*)d_in[3];
    const float* bq   = (const float*)d_in[4];
    const float* wk   = (const float*)d_in[5];
    const float* bk   = (const float*)d_in[6];
    const float* wv   = (const float*)d_in[7];
    const float* bv   = (const float*)d_in[8];
    const float* wo   = (const float*)d_in[9];
    const float* bo   = (const float*)d_in[10];
    const float* ln2w = (const float*)d_in[11];
    const float* ln2b = (const float*)d_in[12];
    const float* w1   = (const float*)d_in[13];
    const float* b1   = (const float*)d_in[14];
    const float* w2   = (const float*)d_in[15];
    const float* b2   = (const float*)d_in[16];

    char* p = (char*)d_ws;
    size_t off = 0;
    auto alloc = [&](size_t bytes) {
        char* r = p + off;
        off += (bytes + 255) & ~(size_t)255;
        return (void*)r;
    };
    const int M = M_TOK;
    // weight block: MUST stay contiguous in this order (cvt_all writes linearly)
    u16* wqkvb = (u16*)alloc((size_t)3 * D_DIM * D_DIM * 2);  // [3072][1024]
    u16* wob   = (u16*)alloc((size_t)D_DIM * D_DIM * 2);
    u16* w1b   = (u16*)alloc((size_t)FF_DIM * D_DIM * 2);
    u16* w2b   = (u16*)alloc((size_t)D_DIM * FF_DIM * 2);
    float* bqkv = (float*)alloc((size_t)3 * D_DIM * 4);
    u16*  x_ln = (u16*) alloc((size_t)M * D_DIM * 2);
    u16*  qb   = (u16*) alloc((size_t)M * D_DIM * 2);
    u16*  kb   = (u16*) alloc((size_t)M * D_DIM * 2);
    u16*  vTb  = (u16*) alloc((size_t)B_SZ * D_DIM * VT_NP * 2);  // 26.2 MB
    u16*  ab   = (u16*) alloc((size_t)M * D_DIM * 2);
    float* hid = (float*)alloc((size_t)M * D_DIM * 4);
    u16*  h1   = qb;  // qb+kb+vT+ab span 89 MB >= M*FF*2 = 84 MB; all dead by FC1

    const int nDD = D_DIM * D_DIM, nFD = FF_DIM * D_DIM;
    const int W8 = (4 * nDD + 2 * nFD) / 8;
    cvt_all_kernel<<<(W8 + 3 * D_DIM + 255) / 256, 256, 0, stream>>>(
        wq, wk, wv, wo, w1, w2, bq, bk, bv, wqkvb, bqkv);

    ln_kernel<<<M, 256, 0, stream>>>(hs, ln1w, ln1b, x_ln);

    const int gM = (M + 127) / 128;  // 81
    dim3 gQKV(gM, 3 * D_DIM / 128);  // 81 x 24
    gemm_kernel<5><<<gQKV, 256, 0, stream>>>(x_ln, wqkvb, bqkv, nullptr,
                                             qb, kb, vTb, M, 3 * D_DIM, D_DIM, 16);

    attn_mfma_kernel<<<5 * H_CNT * B_SZ, 256, 0, stream>>>(qb, kb, vTb, ab);

    dim3 gD(gM, D_DIM / 128);        // 81 x 8
    gemm_kernel<2><<<gD, 256, 0, stream>>>(ab, wob, bo, hs, hid, nullptr, nullptr,
                                           M, D_DIM, D_DIM, 16);

    ln_kernel<<<M, 256, 0, stream>>>(hid, ln2w, ln2b, x_ln);

    dim3 gF(gM, FF_DIM / 128);       // 81 x 32
    gemm_kernel<3><<<gF, 256, 0, stream>>>(x_ln, w1b, b1, nullptr, h1, nullptr, nullptr,
                                           M, FF_DIM, D_DIM, 16);
    gemm_kernel<2><<<gD, 256, 0, stream>>>(h1, w2b, b2, hid, (float*)d_out,
                                           nullptr, nullptr, M, D_DIM, FF_DIM, 4);
}